// Round 3
// baseline (49.470 us; speedup 1.0000x reference)
//
#include <hip/hip_runtime.h>
#include <hip/hip_bf16.h>

#define NVIS 16384
#define EMB 128
#define HID 64
#define MED 153
#define K1 384

typedef float f32x4 __attribute__((ext_vector_type(4)));
typedef short s16x8 __attribute__((ext_vector_type(8)));
typedef unsigned int u32;

__device__ __forceinline__ unsigned short f2bf(float f) {
  union { float f; unsigned u; } v; v.f = f;
  unsigned r = v.u + 0x7FFFu + ((v.u >> 16) & 1u);   // round-to-nearest-even
  return (unsigned short)(r >> 16);
}

__device__ __forceinline__ int lower_bound_rng(const int* __restrict__ a, int lo, int hi, int key) {
  while (lo < hi) {
    int mid = (lo + hi) >> 1;
    if (a[mid] < key) lo = mid + 1; else hi = mid;
  }
  return lo;
}

// interpolation-bracketed lower_bound: seg values ~uniform over [0,16384)
__device__ __forceinline__ int lower_bound_fast(const int* __restrict__ a, int n, int key) {
  long long g = ((long long)key * (long long)n) >> 14;   // key * n / 16384
  int L = (int)g - 3072, R = (int)g + 3072;
  if (L < 0) L = 0;
  if (R > n) R = n;
  const bool ok = (L == 0 || a[L - 1] < key) && (R == n || a[R] >= key);
  if (!ok) { L = 0; R = n; }   // fallback: full range (always correct)
  return lower_bound_rng(a, L, R, key);
}

// ================= Kernel 1: gather + segment-sum -> x bf16 [NVIS][384] =================
#define GV 8   // visits per block; one 32-lane half-wave per visit
__global__ __launch_bounds__(256, 8) void gather_kernel(
    const int* __restrict__ diag_codes, const int* __restrict__ diag_seg,
    const int* __restrict__ proc_codes, const int* __restrict__ proc_seg,
    const int* __restrict__ med_codes,  const int* __restrict__ med_seg,
    const float* __restrict__ diag_table, const float* __restrict__ proc_table,
    const float* __restrict__ med_table,
    unsigned short* __restrict__ x, int ND, int NP, int NM)
{
  __shared__ int offs[3][GV + 1];
  const int tid = threadIdx.x;
  const int v0 = blockIdx.x * GV;

  if (tid < 27) {
    const int T = tid / 9, idx = tid - T * 9;
    const int* seg = (T == 0) ? diag_seg : (T == 1) ? proc_seg : med_seg;
    const int n = (T == 0) ? ND : (T == 1) ? NP : NM;
    offs[T][idx] = lower_bound_fast(seg, n, v0 + idx);
  }
  __syncthreads();

  const int half = tid >> 5;          // 0..7 -> visit v0+half
  const int ln = tid & 31;            // lane owns dims ln*4 .. ln*4+3
  unsigned short* xrow = x + (size_t)(v0 + half) * K1;

#define GATH(T, CODES, TBL)                                                        \
  {                                                                                \
    const int s_ = offs[T][half], e_ = offs[T][half + 1];                          \
    float a0 = 0.f, a1 = 0.f, a2 = 0.f, a3 = 0.f;                                  \
    int i = s_;                                                                    \
    for (; i + 3 < e_; i += 4) {                                                   \
      const int c0 = CODES[i], c1 = CODES[i + 1];                                  \
      const int c2 = CODES[i + 2], c3 = CODES[i + 3];                              \
      const f32x4 t0 = *(const f32x4*)(TBL + (size_t)c0 * EMB + ln * 4);           \
      const f32x4 t1 = *(const f32x4*)(TBL + (size_t)c1 * EMB + ln * 4);           \
      const f32x4 t2 = *(const f32x4*)(TBL + (size_t)c2 * EMB + ln * 4);           \
      const f32x4 t3 = *(const f32x4*)(TBL + (size_t)c3 * EMB + ln * 4);           \
      a0 += (t0[0] + t1[0]) + (t2[0] + t3[0]);                                     \
      a1 += (t0[1] + t1[1]) + (t2[1] + t3[1]);                                     \
      a2 += (t0[2] + t1[2]) + (t2[2] + t3[2]);                                     \
      a3 += (t0[3] + t1[3]) + (t2[3] + t3[3]);                                     \
    }                                                                              \
    for (; i < e_; ++i) {                                                          \
      const int c = CODES[i];                                                      \
      const f32x4 t = *(const f32x4*)(TBL + (size_t)c * EMB + ln * 4);             \
      a0 += t[0]; a1 += t[1]; a2 += t[2]; a3 += t[3];                              \
    }                                                                              \
    const u32 p0 = (u32)f2bf(a0) | ((u32)f2bf(a1) << 16);                          \
    const u32 p1 = (u32)f2bf(a2) | ((u32)f2bf(a3) << 16);                          \
    u32* d_ = (u32*)(xrow + T * EMB + ln * 4);                                     \
    d_[0] = p0; d_[1] = p1;                                                        \
  }

  GATH(0, diag_codes, diag_table)
  GATH(1, proc_codes, proc_table)
  GATH(2, med_codes,  med_table)
#undef GATH
}

// ================= Kernel 2: MLP  out = sigmoid(relu(x@W1+b1)@W2+b2) =================
#define MT 32   // rows per block
__global__ __launch_bounds__(256, 2) void mlp_kernel(
    const unsigned short* __restrict__ x,
    const float* __restrict__ W1, const float* __restrict__ b1,
    const float* __restrict__ W2, const float* __restrict__ b2,
    float* __restrict__ out)
{
  __shared__ __align__(16) unsigned short hs[MT][HID + 8];

  const int tid = threadIdx.x;
  const int l = tid & 63;
  const int wv = tid >> 6;
  const int jloc = l & 15;
  const int kq = l >> 4;
  const int m0 = blockIdx.x * MT;
  const int j1 = wv * 16 + jloc;     // W1 output column owned by this wave

  // B fragments of W1 (col j1), k = kt*32 + kq*8 + e
  s16x8 bfr[12];
  #pragma unroll
  for (int kt = 0; kt < 12; ++kt) {
    const int kb = kt * 32 + kq * 8;
    s16x8 bf;
    #pragma unroll
    for (int e = 0; e < 8; ++e)
      bf[e] = (short)f2bf(W1[(size_t)(kb + e) * HID + j1]);
    bfr[kt] = bf;
  }

  // GEMM1: A fragments straight from global x (L2-resident, full-line txns)
  f32x4 acc0 = {0.f, 0.f, 0.f, 0.f};
  f32x4 acc1 = {0.f, 0.f, 0.f, 0.f};
  #pragma unroll
  for (int kt = 0; kt < 12; ++kt) {
    const int ko = kt * 32 + kq * 8;
    const s16x8 a0 = *(const s16x8*)(x + (size_t)(m0 + jloc) * K1 + ko);
    const s16x8 a1 = *(const s16x8*)(x + (size_t)(m0 + jloc + 16) * K1 + ko);
    acc0 = __builtin_amdgcn_mfma_f32_16x16x32_bf16(a0, bfr[kt], acc0, 0, 0, 0);
    acc1 = __builtin_amdgcn_mfma_f32_16x16x32_bf16(a1, bfr[kt], acc1, 0, 0, 0);
  }

  {
    const float bias1 = b1[j1];
    #pragma unroll
    for (int r = 0; r < 4; ++r) {
      const int vr = kq * 4 + r;      // D: col=l&15, row=(l>>4)*4+reg
      hs[vr][j1]      = f2bf(fmaxf(acc0[r] + bias1, 0.f));
      hs[vr + 16][j1] = f2bf(fmaxf(acc1[r] + bias1, 0.f));
    }
  }
  __syncthreads();

  // GEMM2: out[32][153] = sigmoid(h @ W2 + b2); N padded to 160 -> 10 tiles
  for (int t = wv; t < 10; t += 4) {
    const int n = t * 16 + jloc;
    const bool nok = (n < MED);
    s16x8 bw0, bw1;
    #pragma unroll
    for (int e = 0; e < 8; ++e) {
      const int k0 = kq * 8 + e;
      bw0[e] = nok ? (short)f2bf(W2[(size_t)k0 * MED + n])        : (short)0;
      bw1[e] = nok ? (short)f2bf(W2[(size_t)(k0 + 32) * MED + n]) : (short)0;
    }
    f32x4 o0 = {0.f, 0.f, 0.f, 0.f};
    f32x4 o1 = {0.f, 0.f, 0.f, 0.f};
    {
      const int ko = kq * 8;
      const s16x8 a00 = *(const s16x8*)&hs[jloc][ko];
      const s16x8 a10 = *(const s16x8*)&hs[jloc + 16][ko];
      o0 = __builtin_amdgcn_mfma_f32_16x16x32_bf16(a00, bw0, o0, 0, 0, 0);
      o1 = __builtin_amdgcn_mfma_f32_16x16x32_bf16(a10, bw0, o1, 0, 0, 0);
      const s16x8 a01 = *(const s16x8*)&hs[jloc][ko + 32];
      const s16x8 a11 = *(const s16x8*)&hs[jloc + 16][ko + 32];
      o0 = __builtin_amdgcn_mfma_f32_16x16x32_bf16(a01, bw1, o0, 0, 0, 0);
      o1 = __builtin_amdgcn_mfma_f32_16x16x32_bf16(a11, bw1, o1, 0, 0, 0);
    }
    if (nok) {
      const float bias2 = b2[n];
      #pragma unroll
      for (int r = 0; r < 4; ++r) {
        const int row = kq * 4 + r;
        const float z0 = o0[r] + bias2;
        const float z1 = o1[r] + bias2;
        out[(size_t)(m0 + row) * MED + n]      = 1.f / (1.f + __expf(-z0));
        out[(size_t)(m0 + row + 16) * MED + n] = 1.f / (1.f + __expf(-z1));
      }
    }
  }
}

// ================= Fallback: round-2 fused kernel (used only if ws too small) =================
#define VPB 16
#define NBLK (NVIS / VPB)
#define CAPD 640
#define CAPP 384
#define CAPM 512
#define CAPT (CAPD + CAPP + CAPM)

__global__ __launch_bounds__(256, 4) void fused_ehr_kernel(
    const int* __restrict__ diag_codes, const int* __restrict__ diag_seg,
    const int* __restrict__ proc_codes, const int* __restrict__ proc_seg,
    const int* __restrict__ med_codes,  const int* __restrict__ med_seg,
    const float* __restrict__ diag_table, const float* __restrict__ proc_table,
    const float* __restrict__ med_table,
    const float* __restrict__ W1, const float* __restrict__ b1,
    const float* __restrict__ W2, const float* __restrict__ b2,
    float* __restrict__ out, int ND, int NP, int NM)
{
  __shared__ __align__(16) unsigned short xs[VPB][K1 + 8];
  __shared__ __align__(16) unsigned short hs[VPB][HID + 8];
  __shared__ int offs[3][VPB + 1];
  __shared__ int codesL[CAPT];
  __shared__ int segL[CAPT];

  const int tid = threadIdx.x;
  const int b0 = blockIdx.x * VPB;

  if (tid < 6) {
    const int T = tid >> 1, w = tid & 1;
    const int* seg = (T == 0) ? diag_seg : (T == 1) ? proc_seg : med_seg;
    const int n = (T == 0) ? ND : (T == 1) ? NP : NM;
    offs[T][w ? VPB : 0] = lower_bound_fast(seg, n, b0 + (w ? VPB : 0));
  }
  __syncthreads();

  const int sD = offs[0][0], cntD = offs[0][VPB] - sD;
  const int sP = offs[1][0], cntP = offs[1][VPB] - sP;
  const int sM = offs[2][0], cntM = offs[2][VPB] - sM;
  const bool stD = (cntD <= CAPD), stP = (cntP <= CAPP), stM = (cntM <= CAPM);

  if (tid < 3 * (VPB - 1)) {
    const int T = tid / (VPB - 1), idx = tid - T * (VPB - 1) + 1;
    offs[T][idx] = offs[T][VPB];
  }
  if (stD) for (int i = tid; i < cntD; i += 256) { codesL[i] = diag_codes[sD + i]; segL[i] = diag_seg[sD + i]; }
  if (stP) for (int i = tid; i < cntP; i += 256) { codesL[CAPD + i] = proc_codes[sP + i]; segL[CAPD + i] = proc_seg[sP + i]; }
  if (stM) for (int i = tid; i < cntM; i += 256) { codesL[CAPD + CAPP + i] = med_codes[sM + i]; segL[CAPD + CAPP + i] = med_seg[sM + i]; }
  __syncthreads();

#define MARK(Tidx, STAGED, CNT, SBASE, LBASE, SEGG, NT)                          \
  if (STAGED) {                                                                  \
    for (int i = tid; i < CNT; i += 256) {                                       \
      const int v1 = segL[LBASE + i];                                            \
      const int v0_ = (i == 0) ? (b0 - 1) : segL[LBASE + i - 1];                 \
      int klo = v0_ + 1; if (klo < b0 + 1) klo = b0 + 1;                         \
      int khi = v1;      if (khi > b0 + VPB - 1) khi = b0 + VPB - 1;             \
      for (int k = klo; k <= khi; ++k) offs[Tidx][k - b0] = SBASE + i;           \
    }                                                                            \
  } else if (tid < VPB - 1) {                                                    \
    offs[Tidx][tid + 1] = lower_bound_fast(SEGG, NT, b0 + tid + 1);              \
  }

  MARK(0, stD, cntD, sD, 0,           diag_seg, ND)
  MARK(1, stP, cntP, sP, CAPD,        proc_seg, NP)
  MARK(2, stM, cntM, sM, CAPD + CAPP, med_seg,  NM)
#undef MARK
  __syncthreads();

  const int l = tid & 63;
  const int wv = tid >> 6;
  const int chunk = l & 31;
  const int slot = l >> 5;

#define GATHER_TABLE(Tidx, TBL, CODES_G, STAGED, SGLOB, LBASE)                      \
    {                                                                               \
      const int s_ = offs[Tidx][v], e_ = offs[Tidx][v + 1];                         \
      float a0 = 0.f, a1 = 0.f, a2 = 0.f, a3 = 0.f;                                 \
      int i = s_ + slot;                                                            \
      if (STAGED) {                                                                 \
        const int lb = LBASE - SGLOB;                                               \
        for (; i + 6 < e_; i += 8) {                                                \
          const int c0 = codesL[lb + i];                                            \
          const int c1 = codesL[lb + i + 2];                                        \
          const int c2 = codesL[lb + i + 4];                                        \
          const int c3 = codesL[lb + i + 6];                                        \
          const f32x4 t0 = *(const f32x4*)(TBL + (size_t)c0 * EMB + chunk * 4);     \
          const f32x4 t1 = *(const f32x4*)(TBL + (size_t)c1 * EMB + chunk * 4);     \
          const f32x4 t2 = *(const f32x4*)(TBL + (size_t)c2 * EMB + chunk * 4);     \
          const f32x4 t3 = *(const f32x4*)(TBL + (size_t)c3 * EMB + chunk * 4);     \
          a0 += (t0[0] + t1[0]) + (t2[0] + t3[0]);                                  \
          a1 += (t0[1] + t1[1]) + (t2[1] + t3[1]);                                  \
          a2 += (t0[2] + t1[2]) + (t2[2] + t3[2]);                                  \
          a3 += (t0[3] + t1[3]) + (t2[3] + t3[3]);                                  \
        }                                                                           \
        for (; i < e_; i += 2) {                                                    \
          const int c = codesL[lb + i];                                             \
          const f32x4 t = *(const f32x4*)(TBL + (size_t)c * EMB + chunk * 4);       \
          a0 += t[0]; a1 += t[1]; a2 += t[2]; a3 += t[3];                           \
        }                                                                           \
      } else {                                                                      \
        for (; i < e_; i += 2) {                                                    \
          const int c = CODES_G[i];                                                 \
          const f32x4 t = *(const f32x4*)(TBL + (size_t)c * EMB + chunk * 4);       \
          a0 += t[0]; a1 += t[1]; a2 += t[2]; a3 += t[3];                           \
        }                                                                           \
      }                                                                             \
      a0 += __shfl_xor(a0, 32); a1 += __shfl_xor(a1, 32);                           \
      a2 += __shfl_xor(a2, 32); a3 += __shfl_xor(a3, 32);                           \
      if (slot == 0) {                                                              \
        unsigned p0 = (unsigned)f2bf(a0) | ((unsigned)f2bf(a1) << 16);              \
        unsigned p1 = (unsigned)f2bf(a2) | ((unsigned)f2bf(a3) << 16);              \
        unsigned* dst_ = (unsigned*)&xs[v][Tidx * EMB + chunk * 4];                 \
        dst_[0] = p0; dst_[1] = p1;                                                 \
      }                                                                             \
    }

  #pragma unroll 1
  for (int it = 0; it < VPB / 4; ++it) {
    const int v = wv * (VPB / 4) + it;
    GATHER_TABLE(0, diag_table, diag_codes, stD, sD, 0)
    GATHER_TABLE(1, proc_table, proc_codes, stP, sP, CAPD)
    GATHER_TABLE(2, med_table,  med_codes,  stM, sM, CAPD + CAPP)
  }
#undef GATHER_TABLE
  __syncthreads();

  const int jloc = l & 15;
  const int kq = l >> 4;
  const int j1 = wv * 16 + jloc;

  s16x8 bfr[12];
  #pragma unroll
  for (int kt = 0; kt < 12; ++kt) {
    const int kb = kt * 32 + kq * 8;
    s16x8 bf;
    #pragma unroll
    for (int e = 0; e < 8; ++e)
      bf[e] = (short)f2bf(W1[(kb + e) * HID + j1]);
    bfr[kt] = bf;
  }

  f32x4 acc = {0.f, 0.f, 0.f, 0.f};
  #pragma unroll
  for (int kt = 0; kt < 12; ++kt) {
    const int ko = kt * 32 + kq * 8;
    const s16x8 a0 = *(const s16x8*)&xs[jloc][ko];
    acc = __builtin_amdgcn_mfma_f32_16x16x32_bf16(a0, bfr[kt], acc, 0, 0, 0);
  }

  {
    const float bias1 = b1[j1];
    #pragma unroll
    for (int r = 0; r < 4; ++r) {
      const int vr = kq * 4 + r;
      hs[vr][j1] = f2bf(fmaxf(acc[r] + bias1, 0.f));
    }
  }
  __syncthreads();

  for (int t = wv; t < 10; t += 4) {
    const int n = t * 16 + jloc;
    const bool nok = (n < MED);
    s16x8 bw0, bw1;
    #pragma unroll
    for (int e = 0; e < 8; ++e) {
      const int k0 = kq * 8 + e;
      bw0[e] = nok ? (short)f2bf(W2[k0 * MED + n])        : (short)0;
      bw1[e] = nok ? (short)f2bf(W2[(k0 + 32) * MED + n]) : (short)0;
    }
    f32x4 o0 = {0.f, 0.f, 0.f, 0.f};
    {
      const int ko = kq * 8;
      const s16x8 a00 = *(const s16x8*)&hs[jloc][ko];
      o0 = __builtin_amdgcn_mfma_f32_16x16x32_bf16(a00, bw0, o0, 0, 0, 0);
      const s16x8 a01 = *(const s16x8*)&hs[jloc][ko + 32];
      o0 = __builtin_amdgcn_mfma_f32_16x16x32_bf16(a01, bw1, o0, 0, 0, 0);
    }
    if (nok) {
      const float bias2 = b2[n];
      #pragma unroll
      for (int r = 0; r < 4; ++r) {
        const int row = kq * 4 + r;
        const float z0 = o0[r] + bias2;
        out[(size_t)(b0 + row) * MED + n] = 1.f / (1.f + __expf(-z0));
      }
    }
  }
}

extern "C" void kernel_launch(void* const* d_in, const int* in_sizes, int n_in,
                              void* d_out, int out_size, void* d_ws, size_t ws_size,
                              hipStream_t stream) {
  const int* diag_codes = (const int*)d_in[0];
  const int* diag_seg   = (const int*)d_in[1];
  const int* proc_codes = (const int*)d_in[2];
  const int* proc_seg   = (const int*)d_in[3];
  const int* med_codes  = (const int*)d_in[4];
  const int* med_seg    = (const int*)d_in[5];
  const float* diag_table = (const float*)d_in[6];
  const float* proc_table = (const float*)d_in[7];
  const float* med_table  = (const float*)d_in[8];
  const float* W1 = (const float*)d_in[9];
  const float* b1 = (const float*)d_in[10];
  const float* W2 = (const float*)d_in[11];
  const float* b2 = (const float*)d_in[12];
  float* out = (float*)d_out;

  const size_t xbytes = (size_t)NVIS * K1 * sizeof(unsigned short);
  if (ws_size >= xbytes) {
    unsigned short* x = (unsigned short*)d_ws;
    gather_kernel<<<dim3(NVIS / GV), dim3(256), 0, stream>>>(
        diag_codes, diag_seg, proc_codes, proc_seg, med_codes, med_seg,
        diag_table, proc_table, med_table, x,
        in_sizes[0], in_sizes[2], in_sizes[4]);
    mlp_kernel<<<dim3(NVIS / MT), dim3(256), 0, stream>>>(x, W1, b1, W2, b2, out);
  } else {
    fused_ehr_kernel<<<dim3(NBLK), dim3(256), 0, stream>>>(
        diag_codes, diag_seg, proc_codes, proc_seg, med_codes, med_seg,
        diag_table, proc_table, med_table, W1, b1, W2, b2, out,
        in_sizes[0], in_sizes[2], in_sizes[4]);
  }
}

// Round 4
// 35.558 us; speedup vs baseline: 1.3912x; 1.3912x over previous
//
#include <hip/hip_runtime.h>
#include <hip/hip_bf16.h>

#define NVIS 16384
#define EMB 128
#define HID 64
#define MED 153
#define K1 384
#define VPB 16
#define NTHR 512
#define NBLK (NVIS / VPB)    // 1024 blocks x 512 thr = 4 blocks/CU, 32 waves/CU
#define CAPD 640
#define CAPP 384
#define CAPM 512
#define CAPT (CAPD + CAPP + CAPM)

typedef float f32x4 __attribute__((ext_vector_type(4)));
typedef short s16x8 __attribute__((ext_vector_type(8)));
typedef unsigned int u32;

__device__ __forceinline__ unsigned short f2bf(float f) {
  union { float f; unsigned u; } v; v.f = f;
  unsigned r = v.u + 0x7FFFu + ((v.u >> 16) & 1u);   // round-to-nearest-even
  return (unsigned short)(r >> 16);
}

__device__ __forceinline__ int lb_scalar(const int* __restrict__ a, int lo, int hi, int key) {
  while (lo < hi) {
    int mid = (lo + hi) >> 1;
    if (a[mid] < key) lo = mid + 1; else hi = mid;
  }
  return lo;
}

// scalar interpolation-bracketed lower_bound (fallback paths only)
__device__ __forceinline__ int lb_fast_scalar(const int* __restrict__ a, int n, int key) {
  long long g = ((long long)key * (long long)n) >> 14;
  int L = (int)g - 3072, R = (int)g + 3072;
  if (L < 0) L = 0;
  if (R > n) R = n;
  const bool ok = (L == 0 || a[L - 1] < key) && (R == n || a[R] >= key);
  if (!ok) { L = 0; R = n; }
  return lb_scalar(a, L, R, key);
}

// wave-parallel lower_bound: all 64 lanes participate, returns uniform result.
// Invariant: a[lo] < key <= a[hi] (virtual sentinels at -1 / n).
__device__ __forceinline__ int lb_wave(const int* __restrict__ a, int n, int key, int lane) {
  long long g = ((long long)key * (long long)n) >> 14;
  int L = (int)g - 3072, R = (int)g + 3072;
  if (L < 0) L = 0;
  if (R > n) R = n;
  const bool ok = (L == 0 || a[L - 1] < key) && (R == n || a[R] >= key);
  if (!ok) { L = 0; R = n; }
  int lo = L - 1, hi = R;
  while (hi - lo > 1) {
    const int width = hi - lo - 1;                       // candidates in (lo, hi)
    const int p = lo + 1 + (int)(((long long)width * lane) >> 6);
    const bool lt = a[p] < key;                          // monotone non-increasing in lane
    const unsigned long long m = __ballot(lt);
    const int t = m ? (63 - __builtin_clzll(m)) : -1;    // last true lane
    const int nlo = (t >= 0) ? lo + 1 + (int)(((long long)width * t) >> 6) : lo;
    const int nhi = (t < 63) ? lo + 1 + (int)(((long long)width * (t + 1)) >> 6) : hi;
    lo = nlo; hi = nhi;                                  // shrinks by ~64x per step
  }
  return hi;
}

__global__ __launch_bounds__(NTHR, 8) void fused_ehr_kernel(
    const int* __restrict__ diag_codes, const int* __restrict__ diag_seg,
    const int* __restrict__ proc_codes, const int* __restrict__ proc_seg,
    const int* __restrict__ med_codes,  const int* __restrict__ med_seg,
    const float* __restrict__ diag_table, const float* __restrict__ proc_table,
    const float* __restrict__ med_table,
    const float* __restrict__ W1, const float* __restrict__ b1,
    const float* __restrict__ W2, const float* __restrict__ b2,
    float* __restrict__ out, int ND, int NP, int NM)
{
  __shared__ __align__(16) unsigned short xs[VPB][K1 + 8];   // 12544 B
  __shared__ __align__(16) unsigned short hs[VPB][HID + 8];  //  2304 B
  __shared__ int offs[3][VPB + 1];                           //   204 B
  __shared__ int codesL[CAPT];                               //  6144 B  (total ~21.2 KB)

  const int tid = threadIdx.x;
  const int l = tid & 63;
  const int wv = tid >> 6;          // 8 waves
  const int b0 = blockIdx.x * VPB;

  // ---- 6 end-boundary searches, one per wave (waves 0-5), 64-ary ----
  if (wv < 6) {
    const int T = wv >> 1, w = wv & 1;
    const int* seg = (T == 0) ? diag_seg : (T == 1) ? proc_seg : med_seg;
    const int n = (T == 0) ? ND : (T == 1) ? NP : NM;
    const int r = lb_wave(seg, n, b0 + (w ? VPB : 0), l);
    if (l == 0) offs[T][w ? VPB : 0] = r;
  }
  __syncthreads();

  const int sD = offs[0][0], cntD = offs[0][VPB] - sD;
  const int sP = offs[1][0], cntP = offs[1][VPB] - sP;
  const int sM = offs[2][0], cntM = offs[2][VPB] - sM;
  const bool stD = (cntD <= CAPD), stP = (cntP <= CAPP), stM = (cntM <= CAPM);

  // init interior boundaries to the end (correct when no staged elem >= key)
  if (tid < 3 * (VPB - 1)) {
    const int T = tid / (VPB - 1), idx = tid - T * (VPB - 1) + 1;
    offs[T][idx] = offs[T][VPB];
  }
  // stage code windows (coalesced)
  if (stD) for (int i = tid; i < cntD; i += NTHR) codesL[i] = diag_codes[sD + i];
  if (stP) for (int i = tid; i < cntP; i += NTHR) codesL[CAPD + i] = proc_codes[sP + i];
  if (stM) for (int i = tid; i < cntM; i += NTHR) codesL[CAPD + CAPP + i] = med_codes[sM + i];
  __syncthreads();

  // ---- interior boundary marking; seg read from global (L2-hot), conflict-free ----
#define MARK(Tidx, STAGED, CNT, SBASE, SEGG, NT)                                 \
  if (STAGED) {                                                                  \
    for (int i = tid; i < CNT; i += NTHR) {                                      \
      const int v1 = SEGG[SBASE + i];                                            \
      const int v0_ = (i == 0) ? (b0 - 1) : SEGG[SBASE + i - 1];                 \
      int klo = v0_ + 1; if (klo < b0 + 1) klo = b0 + 1;                         \
      int khi = v1;      if (khi > b0 + VPB - 1) khi = b0 + VPB - 1;             \
      for (int k = klo; k <= khi; ++k) offs[Tidx][k - b0] = SBASE + i;           \
    }                                                                            \
  } else if (tid < VPB - 1) {                                                    \
    offs[Tidx][tid + 1] = lb_fast_scalar(SEGG, NT, b0 + tid + 1);                \
  }

  MARK(0, stD, cntD, sD, diag_seg, ND)
  MARK(1, stP, cntP, sP, proc_seg, NP)
  MARK(2, stM, cntM, sM, med_seg,  NM)
#undef MARK
  __syncthreads();

  // ---- gather + segment-sum: one 32-lane half-wave per visit (16 halves = 8 waves) ----
  const int half = tid >> 5;        // visit index 0..15
  const int ln = tid & 31;          // lane owns dims ln*4 .. ln*4+3

#define GATH(T, CODES_G, TBL, STAGED, SGLOB, LBASE)                               \
  {                                                                               \
    const int s_ = offs[T][half], e_ = offs[T][half + 1];                         \
    float a0 = 0.f, a1 = 0.f, a2 = 0.f, a3 = 0.f;                                 \
    int i = s_;                                                                   \
    if (STAGED) {                                                                 \
      const int lb = LBASE - SGLOB;                                               \
      for (; i + 3 < e_; i += 4) {                                                \
        const int c0 = codesL[lb + i],     c1 = codesL[lb + i + 1];               \
        const int c2 = codesL[lb + i + 2], c3 = codesL[lb + i + 3];               \
        const f32x4 t0 = *(const f32x4*)(TBL + (size_t)c0 * EMB + ln * 4);        \
        const f32x4 t1 = *(const f32x4*)(TBL + (size_t)c1 * EMB + ln * 4);        \
        const f32x4 t2 = *(const f32x4*)(TBL + (size_t)c2 * EMB + ln * 4);        \
        const f32x4 t3 = *(const f32x4*)(TBL + (size_t)c3 * EMB + ln * 4);        \
        a0 += (t0[0] + t1[0]) + (t2[0] + t3[0]);                                  \
        a1 += (t0[1] + t1[1]) + (t2[1] + t3[1]);                                  \
        a2 += (t0[2] + t1[2]) + (t2[2] + t3[2]);                                  \
        a3 += (t0[3] + t1[3]) + (t2[3] + t3[3]);                                  \
      }                                                                           \
      for (; i < e_; ++i) {                                                       \
        const int c = codesL[lb + i];                                             \
        const f32x4 t = *(const f32x4*)(TBL + (size_t)c * EMB + ln * 4);          \
        a0 += t[0]; a1 += t[1]; a2 += t[2]; a3 += t[3];                           \
      }                                                                           \
    } else {                                                                      \
      for (; i < e_; ++i) {                                                       \
        const int c = CODES_G[i];                                                 \
        const f32x4 t = *(const f32x4*)(TBL + (size_t)c * EMB + ln * 4);          \
        a0 += t[0]; a1 += t[1]; a2 += t[2]; a3 += t[3];                           \
      }                                                                           \
    }                                                                             \
    const u32 p0 = (u32)f2bf(a0) | ((u32)f2bf(a1) << 16);                         \
    const u32 p1 = (u32)f2bf(a2) | ((u32)f2bf(a3) << 16);                         \
    uint2* d_ = (uint2*)&xs[half][T * EMB + ln * 4];                              \
    *d_ = make_uint2(p0, p1);                                                     \
  }

  GATH(0, diag_codes, diag_table, stD, sD, 0)
  GATH(1, proc_codes, proc_table, stP, sP, CAPD)
  GATH(2, med_codes,  med_table,  stM, sM, CAPD + CAPP)
#undef GATH
  __syncthreads();

  // ---- GEMM1 (waves 0-3): h[16][64] = relu(x @ W1 + b1), bf16 MFMA 16x16x32 ----
  // A frag: row=l&15, k=(l>>4)*8+e.  B frag: col=l&15, k=(l>>4)*8+e.
  // D: col=l&15, row=(l>>4)*4+reg (m89-verified).
  const int jloc = l & 15;
  const int kq = l >> 4;

  if (wv < 4) {
    const int j1 = wv * 16 + jloc;
    f32x4 acc = {0.f, 0.f, 0.f, 0.f};
    s16x8 bf;
    #pragma unroll
    for (int e = 0; e < 8; ++e)
      bf[e] = (short)f2bf(W1[(size_t)(kq * 8 + e) * HID + j1]);
    #pragma unroll
    for (int kt = 0; kt < 12; ++kt) {
      s16x8 nxt;
      if (kt < 11) {
        const int kb = (kt + 1) * 32 + kq * 8;
        #pragma unroll
        for (int e = 0; e < 8; ++e)
          nxt[e] = (short)f2bf(W1[(size_t)(kb + e) * HID + j1]);
      }
      const s16x8 a0 = *(const s16x8*)&xs[jloc][kt * 32 + kq * 8];
      acc = __builtin_amdgcn_mfma_f32_16x16x32_bf16(a0, bf, acc, 0, 0, 0);
      if (kt < 11) bf = nxt;
    }
    const float bias1 = b1[j1];
    #pragma unroll
    for (int r = 0; r < 4; ++r)
      hs[kq * 4 + r][j1] = f2bf(fmaxf(acc[r] + bias1, 0.f));
  }
  __syncthreads();

  // ---- GEMM2 (all 8 waves): out[16][153] = sigmoid(h @ W2 + b2); 10 N-tiles ----
  for (int t = wv; t < 10; t += 8) {
    const int n = t * 16 + jloc;
    const bool nok = (n < MED);
    s16x8 bw0, bw1;
    #pragma unroll
    for (int e = 0; e < 8; ++e) {
      const int k0 = kq * 8 + e;
      bw0[e] = nok ? (short)f2bf(W2[(size_t)k0 * MED + n])        : (short)0;
      bw1[e] = nok ? (short)f2bf(W2[(size_t)(k0 + 32) * MED + n]) : (short)0;
    }
    f32x4 o0 = {0.f, 0.f, 0.f, 0.f};
    {
      const int ko = kq * 8;
      const s16x8 a00 = *(const s16x8*)&hs[jloc][ko];
      o0 = __builtin_amdgcn_mfma_f32_16x16x32_bf16(a00, bw0, o0, 0, 0, 0);
      const s16x8 a01 = *(const s16x8*)&hs[jloc][ko + 32];
      o0 = __builtin_amdgcn_mfma_f32_16x16x32_bf16(a01, bw1, o0, 0, 0, 0);
    }
    if (nok) {
      const float bias2 = b2[n];
      #pragma unroll
      for (int r = 0; r < 4; ++r) {
        const int row = kq * 4 + r;
        const float z0 = o0[r] + bias2;
        out[(size_t)(b0 + row) * MED + n] = 1.f / (1.f + __expf(-z0));
      }
    }
  }
}

extern "C" void kernel_launch(void* const* d_in, const int* in_sizes, int n_in,
                              void* d_out, int out_size, void* d_ws, size_t ws_size,
                              hipStream_t stream) {
  const int* diag_codes = (const int*)d_in[0];
  const int* diag_seg   = (const int*)d_in[1];
  const int* proc_codes = (const int*)d_in[2];
  const int* proc_seg   = (const int*)d_in[3];
  const int* med_codes  = (const int*)d_in[4];
  const int* med_seg    = (const int*)d_in[5];
  const float* diag_table = (const float*)d_in[6];
  const float* proc_table = (const float*)d_in[7];
  const float* med_table  = (const float*)d_in[8];
  const float* W1 = (const float*)d_in[9];
  const float* b1 = (const float*)d_in[10];
  const float* W2 = (const float*)d_in[11];
  const float* b2 = (const float*)d_in[12];
  float* out = (float*)d_out;

  fused_ehr_kernel<<<dim3(NBLK), dim3(NTHR), 0, stream>>>(
      diag_codes, diag_seg, proc_codes, proc_seg, med_codes, med_seg,
      diag_table, proc_table, med_table, W1, b1, W2, b2, out,
      in_sizes[0], in_sizes[2], in_sizes[4]);
}

// Round 5
// 30.371 us; speedup vs baseline: 1.6288x; 1.1708x over previous
//
#include <hip/hip_runtime.h>
#include <hip/hip_bf16.h>

#define NVIS 16384
#define EMB 128
#define HID 64
#define MED 153
#define K1 384
#define VPB 16
#define NTHR 512
#define NBLK (NVIS / VPB)    // 1024 blocks x 512 thr = 4 blocks/CU, 32 waves/CU
#define CAPD 640
#define CAPP 384
#define CAPM 512
#define CAPT (CAPD + CAPP + CAPM)

// ---- d_ws layout (all 16B-aligned) ----
#define W1F_OFF 0u          // 4*12*64 frags * 16B = 49152
#define W2F_OFF 49152u      // 10*2*64 frags * 16B = 20480
#define DIAG_OFF 69632u     // 2000*128 bf16 = 512000
#define PROC_OFF 581632u    // 1500*128 bf16 = 384000
#define MED_OFF  965632u    // 153*128 bf16  = 39168
#define WS_NEED  1004800u

#define TQ_D 32000          // diag  f32-octets (2000*128/8)
#define TQ_P 24000          // proc
#define TQ_M 2448           // med
#define TQ_ALL (TQ_D + TQ_P + TQ_M)          // 58448
#define NW1F 3072
#define NW2F 1280
#define PREP_THREADS (TQ_ALL + NW1F + NW2F)  // 62800
#define PREP_BLOCKS ((PREP_THREADS + 255) / 256)

typedef float f32x4 __attribute__((ext_vector_type(4)));
typedef short s16x8 __attribute__((ext_vector_type(8)));
typedef unsigned int u32;
typedef unsigned int u32x4 __attribute__((ext_vector_type(4)));

__device__ __forceinline__ unsigned short f2bf(float f) {
  union { float f; unsigned u; } v; v.f = f;
  unsigned r = v.u + 0x7FFFu + ((v.u >> 16) & 1u);   // round-to-nearest-even
  return (unsigned short)(r >> 16);
}

__device__ __forceinline__ void acc8(u32x4 t, float& a0, float& a1, float& a2, float& a3,
                                               float& a4, float& a5, float& a6, float& a7) {
  union { unsigned u; float f; } c;
  c.u = t[0] << 16;          a0 += c.f;
  c.u = t[0] & 0xFFFF0000u;  a1 += c.f;
  c.u = t[1] << 16;          a2 += c.f;
  c.u = t[1] & 0xFFFF0000u;  a3 += c.f;
  c.u = t[2] << 16;          a4 += c.f;
  c.u = t[2] & 0xFFFF0000u;  a5 += c.f;
  c.u = t[3] << 16;          a6 += c.f;
  c.u = t[3] & 0xFFFF0000u;  a7 += c.f;
}

__device__ __forceinline__ int lb_scalar(const int* __restrict__ a, int lo, int hi, int key) {
  while (lo < hi) {
    int mid = (lo + hi) >> 1;
    if (a[mid] < key) lo = mid + 1; else hi = mid;
  }
  return lo;
}

__device__ __forceinline__ int lb_fast_scalar(const int* __restrict__ a, int n, int key) {
  long long g = ((long long)key * (long long)n) >> 14;
  int L = (int)g - 3072, R = (int)g + 3072;
  if (L < 0) L = 0;
  if (R > n) R = n;
  const bool ok = (L == 0 || a[L - 1] < key) && (R == n || a[R] >= key);
  if (!ok) { L = 0; R = n; }
  return lb_scalar(a, L, R, key);
}

// wave-parallel lower_bound: all 64 lanes participate, returns uniform result.
__device__ __forceinline__ int lb_wave(const int* __restrict__ a, int n, int key, int lane) {
  long long g = ((long long)key * (long long)n) >> 14;
  int L = (int)g - 3072, R = (int)g + 3072;
  if (L < 0) L = 0;
  if (R > n) R = n;
  const bool ok = (L == 0 || a[L - 1] < key) && (R == n || a[R] >= key);
  if (!ok) { L = 0; R = n; }
  int lo = L - 1, hi = R;
  while (hi - lo > 1) {
    const int width = hi - lo - 1;
    const int p = lo + 1 + (int)(((long long)width * lane) >> 6);
    const bool lt = a[p] < key;
    const unsigned long long m = __ballot(lt);
    const int t = m ? (63 - __builtin_clzll(m)) : -1;
    const int nlo = (t >= 0) ? lo + 1 + (int)(((long long)width * t) >> 6) : lo;
    const int nhi = (t < 63) ? lo + 1 + (int)(((long long)width * (t + 1)) >> 6) : hi;
    lo = nlo; hi = nhi;
  }
  return hi;
}

// ============== prep: f32 tables -> bf16 in ws; W1/W2 -> fragment-order bf16 ==============
__global__ __launch_bounds__(256, 8) void prep_kernel(
    const float* __restrict__ dT, const float* __restrict__ pT, const float* __restrict__ mT,
    const float* __restrict__ W1, const float* __restrict__ W2,
    unsigned char* __restrict__ ws)
{
  const int t = blockIdx.x * 256 + threadIdx.x;
  if (t < TQ_ALL) {
    const float* src; unsigned char* dst; int q;
    if (t < TQ_D)             { src = dT; dst = ws + DIAG_OFF; q = t; }
    else if (t < TQ_D + TQ_P) { src = pT; dst = ws + PROC_OFF; q = t - TQ_D; }
    else                      { src = mT; dst = ws + MED_OFF;  q = t - TQ_D - TQ_P; }
    const f32x4 a = *(const f32x4*)(src + (size_t)q * 8);
    const f32x4 b = *(const f32x4*)(src + (size_t)q * 8 + 4);
    u32x4 o;
    o[0] = (u32)f2bf(a[0]) | ((u32)f2bf(a[1]) << 16);
    o[1] = (u32)f2bf(a[2]) | ((u32)f2bf(a[3]) << 16);
    o[2] = (u32)f2bf(b[0]) | ((u32)f2bf(b[1]) << 16);
    o[3] = (u32)f2bf(b[2]) | ((u32)f2bf(b[3]) << 16);
    *(u32x4*)(dst + (size_t)q * 16) = o;
  } else if (t < TQ_ALL + NW1F) {
    const int idx = t - TQ_ALL;            // (wv*12+kt)*64 + lane
    const int lane = idx & 63, wk = idx >> 6;
    const int kt = wk % 12, wv = wk / 12;
    const int j1 = wv * 16 + (lane & 15);
    const int kb = kt * 32 + (lane >> 4) * 8;
    unsigned short e0[8];
    #pragma unroll
    for (int e = 0; e < 8; ++e) e0[e] = f2bf(W1[(size_t)(kb + e) * HID + j1]);
    u32x4 o;
    o[0] = (u32)e0[0] | ((u32)e0[1] << 16);
    o[1] = (u32)e0[2] | ((u32)e0[3] << 16);
    o[2] = (u32)e0[4] | ((u32)e0[5] << 16);
    o[3] = (u32)e0[6] | ((u32)e0[7] << 16);
    *(u32x4*)(ws + W1F_OFF + (size_t)idx * 16) = o;
  } else if (t < TQ_ALL + NW1F + NW2F) {
    const int idx = t - TQ_ALL - NW1F;     // (tile*2+kh)*64 + lane
    const int lane = idx & 63, tk = idx >> 6;
    const int kh = tk & 1, tile = tk >> 1;
    const int n = tile * 16 + (lane & 15);
    const int k0 = kh * 32 + (lane >> 4) * 8;
    unsigned short e0[8];
    #pragma unroll
    for (int e = 0; e < 8; ++e)
      e0[e] = (n < MED) ? f2bf(W2[(size_t)(k0 + e) * MED + n]) : (unsigned short)0;
    u32x4 o;
    o[0] = (u32)e0[0] | ((u32)e0[1] << 16);
    o[1] = (u32)e0[2] | ((u32)e0[3] << 16);
    o[2] = (u32)e0[4] | ((u32)e0[5] << 16);
    o[3] = (u32)e0[6] | ((u32)e0[7] << 16);
    *(u32x4*)(ws + W2F_OFF + (size_t)idx * 16) = o;
  }
}

// ============== main fused kernel (bf16 tables + pre-swizzled W frags) ==============
__global__ __launch_bounds__(NTHR, 8) void fused_ehr_v5(
    const int* __restrict__ diag_codes, const int* __restrict__ diag_seg,
    const int* __restrict__ proc_codes, const int* __restrict__ proc_seg,
    const int* __restrict__ med_codes,  const int* __restrict__ med_seg,
    const float* __restrict__ b1, const float* __restrict__ b2,
    const unsigned char* __restrict__ ws,
    float* __restrict__ out, int ND, int NP, int NM)
{
  __shared__ __align__(16) unsigned short xs[VPB][K1 + 8];
  __shared__ __align__(16) unsigned short hs[VPB][HID + 8];
  __shared__ int offs[3][VPB + 1];
  __shared__ int codesL[CAPT];

  const int tid = threadIdx.x;
  const int l = tid & 63;
  const int wv = tid >> 6;
  const int b0 = blockIdx.x * VPB;

  // ---- 6 end-boundary searches, one per wave, 64-ary ----
  if (wv < 6) {
    const int T = wv >> 1, w = wv & 1;
    const int* seg = (T == 0) ? diag_seg : (T == 1) ? proc_seg : med_seg;
    const int n = (T == 0) ? ND : (T == 1) ? NP : NM;
    const int r = lb_wave(seg, n, b0 + (w ? VPB : 0), l);
    if (l == 0) offs[T][w ? VPB : 0] = r;
  }
  __syncthreads();

  const int sD = offs[0][0], cntD = offs[0][VPB] - sD;
  const int sP = offs[1][0], cntP = offs[1][VPB] - sP;
  const int sM = offs[2][0], cntM = offs[2][VPB] - sM;
  const bool stD = (cntD <= CAPD), stP = (cntP <= CAPP), stM = (cntM <= CAPM);

  if (tid < 3 * (VPB - 1)) {
    const int T = tid / (VPB - 1), idx = tid - T * (VPB - 1) + 1;
    offs[T][idx] = offs[T][VPB];
  }
  if (stD) for (int i = tid; i < cntD; i += NTHR) codesL[i] = diag_codes[sD + i];
  if (stP) for (int i = tid; i < cntP; i += NTHR) codesL[CAPD + i] = proc_codes[sP + i];
  if (stM) for (int i = tid; i < cntM; i += NTHR) codesL[CAPD + CAPP + i] = med_codes[sM + i];
  __syncthreads();

#define MARK(Tidx, STAGED, CNT, SBASE, SEGG, NT)                                 \
  if (STAGED) {                                                                  \
    for (int i = tid; i < CNT; i += NTHR) {                                      \
      const int v1 = SEGG[SBASE + i];                                            \
      const int v0_ = (i == 0) ? (b0 - 1) : SEGG[SBASE + i - 1];                 \
      int klo = v0_ + 1; if (klo < b0 + 1) klo = b0 + 1;                         \
      int khi = v1;      if (khi > b0 + VPB - 1) khi = b0 + VPB - 1;             \
      for (int k = klo; k <= khi; ++k) offs[Tidx][k - b0] = SBASE + i;           \
    }                                                                            \
  } else if (tid < VPB - 1) {                                                    \
    offs[Tidx][tid + 1] = lb_fast_scalar(SEGG, NT, b0 + tid + 1);                \
  }

  MARK(0, stD, cntD, sD, diag_seg, ND)
  MARK(1, stP, cntP, sP, proc_seg, NP)
  MARK(2, stM, cntM, sM, med_seg,  NM)
#undef MARK
  __syncthreads();

  // ---- gather: one 32-lane half-wave per visit; bf16 table rows (256B) ----
  // 16 lanes cover one row; the two 16-lane groups take even/odd codes.
  const int half = tid >> 5;        // visit 0..15
  const int ln = tid & 31;
  const int pr = ln >> 4;           // code parity within a pair
  const int dd = ln & 15;           // 16B chunk (8 dims) within a 256B row
  const unsigned char* tblD = ws + DIAG_OFF;
  const unsigned char* tblP = ws + PROC_OFF;
  const unsigned char* tblM = ws + MED_OFF;

#define GATHB(T, CODES_G, TBLB, STAGED, SGLOB, LBASE)                             \
  {                                                                               \
    const int s_ = offs[T][half], e_ = offs[T][half + 1];                         \
    float a0=0.f,a1=0.f,a2=0.f,a3=0.f,a4=0.f,a5=0.f,a6=0.f,a7=0.f;                \
    int i = s_;                                                                   \
    if (STAGED) {                                                                 \
      const int lb = LBASE - SGLOB;                                               \
      for (; i + 7 < e_; i += 8) {                                                \
        const int c0 = codesL[lb + i + pr],     c1 = codesL[lb + i + 2 + pr];     \
        const int c2 = codesL[lb + i + 4 + pr], c3 = codesL[lb + i + 6 + pr];     \
        const u32x4 t0 = *(const u32x4*)(TBLB + ((size_t)c0 << 8) + (dd << 4));   \
        const u32x4 t1 = *(const u32x4*)(TBLB + ((size_t)c1 << 8) + (dd << 4));   \
        const u32x4 t2 = *(const u32x4*)(TBLB + ((size_t)c2 << 8) + (dd << 4));   \
        const u32x4 t3 = *(const u32x4*)(TBLB + ((size_t)c3 << 8) + (dd << 4));   \
        acc8(t0, a0,a1,a2,a3,a4,a5,a6,a7);                                        \
        acc8(t1, a0,a1,a2,a3,a4,a5,a6,a7);                                        \
        acc8(t2, a0,a1,a2,a3,a4,a5,a6,a7);                                        \
        acc8(t3, a0,a1,a2,a3,a4,a5,a6,a7);                                        \
      }                                                                           \
      for (; i + pr < e_; i += 2) {                                               \
        const int c = codesL[lb + i + pr];                                        \
        const u32x4 t = *(const u32x4*)(TBLB + ((size_t)c << 8) + (dd << 4));     \
        acc8(t, a0,a1,a2,a3,a4,a5,a6,a7);                                         \
      }                                                                           \
    } else {                                                                      \
      for (; i + pr < e_; i += 2) {                                               \
        const int c = CODES_G[i + pr];                                            \
        const u32x4 t = *(const u32x4*)(TBLB + ((size_t)c << 8) + (dd << 4));     \
        acc8(t, a0,a1,a2,a3,a4,a5,a6,a7);                                         \
      }                                                                           \
    }                                                                             \
    a0 += __shfl_xor(a0, 16); a1 += __shfl_xor(a1, 16);                           \
    a2 += __shfl_xor(a2, 16); a3 += __shfl_xor(a3, 16);                           \
    a4 += __shfl_xor(a4, 16); a5 += __shfl_xor(a5, 16);                           \
    a6 += __shfl_xor(a6, 16); a7 += __shfl_xor(a7, 16);                           \
    if (pr == 0) {                                                                \
      u32x4 o;                                                                    \
      o[0] = (u32)f2bf(a0) | ((u32)f2bf(a1) << 16);                               \
      o[1] = (u32)f2bf(a2) | ((u32)f2bf(a3) << 16);                               \
      o[2] = (u32)f2bf(a4) | ((u32)f2bf(a5) << 16);                               \
      o[3] = (u32)f2bf(a6) | ((u32)f2bf(a7) << 16);                               \
      *(u32x4*)&xs[half][T * EMB + dd * 8] = o;                                   \
    }                                                                             \
  }

  GATHB(0, diag_codes, tblD, stD, sD, 0)
  GATHB(1, proc_codes, tblP, stP, sP, CAPD)
  GATHB(2, med_codes,  tblM, stM, sM, CAPD + CAPP)
#undef GATHB
  __syncthreads();

  // ---- GEMM1 (waves 0-3): h[16][64] = relu(x @ W1 + b1) ----
  // A frag: row=l&15, k=(l>>4)*8+e.  B frag from pre-swizzled w1f (lane-contiguous 16B).
  // D: col=l&15, row=(l>>4)*4+reg (m89-verified).
  const int jloc = l & 15;
  const int kq = l >> 4;
  const s16x8* w1f = (const s16x8*)(ws + W1F_OFF);
  const s16x8* w2f = (const s16x8*)(ws + W2F_OFF);

  if (wv < 4) {
    const int j1 = wv * 16 + jloc;
    f32x4 acc = {0.f, 0.f, 0.f, 0.f};
    #pragma unroll
    for (int kt = 0; kt < 12; ++kt) {
      const s16x8 bf = w1f[(wv * 12 + kt) * 64 + l];
      const s16x8 a0 = *(const s16x8*)&xs[jloc][kt * 32 + kq * 8];
      acc = __builtin_amdgcn_mfma_f32_16x16x32_bf16(a0, bf, acc, 0, 0, 0);
    }
    const float bias1 = b1[j1];
    #pragma unroll
    for (int r = 0; r < 4; ++r)
      hs[kq * 4 + r][j1] = f2bf(fmaxf(acc[r] + bias1, 0.f));
  }
  __syncthreads();

  // ---- GEMM2 (all 8 waves): out[16][153] = sigmoid(h @ W2 + b2); 10 N-tiles ----
  for (int t = wv; t < 10; t += 8) {
    const int n = t * 16 + jloc;
    const bool nok = (n < MED);
    const s16x8 bw0 = w2f[(t * 2 + 0) * 64 + l];
    const s16x8 bw1 = w2f[(t * 2 + 1) * 64 + l];
    f32x4 o0 = {0.f, 0.f, 0.f, 0.f};
    {
      const int ko = kq * 8;
      const s16x8 a00 = *(const s16x8*)&hs[jloc][ko];
      o0 = __builtin_amdgcn_mfma_f32_16x16x32_bf16(a00, bw0, o0, 0, 0, 0);
      const s16x8 a01 = *(const s16x8*)&hs[jloc][ko + 32];
      o0 = __builtin_amdgcn_mfma_f32_16x16x32_bf16(a01, bw1, o0, 0, 0, 0);
    }
    if (nok) {
      const float bias2 = b2[n];
      #pragma unroll
      for (int r = 0; r < 4; ++r) {
        const int row = kq * 4 + r;
        const float z0 = o0[r] + bias2;
        out[(size_t)(b0 + row) * MED + n] = 1.f / (1.f + __expf(-z0));
      }
    }
  }
}

// ============== fallback (round-4 kernel, f32 tables, no ws) ==============
__global__ __launch_bounds__(NTHR, 8) void fused_ehr_fb(
    const int* __restrict__ diag_codes, const int* __restrict__ diag_seg,
    const int* __restrict__ proc_codes, const int* __restrict__ proc_seg,
    const int* __restrict__ med_codes,  const int* __restrict__ med_seg,
    const float* __restrict__ diag_table, const float* __restrict__ proc_table,
    const float* __restrict__ med_table,
    const float* __restrict__ W1, const float* __restrict__ b1,
    const float* __restrict__ W2, const float* __restrict__ b2,
    float* __restrict__ out, int ND, int NP, int NM)
{
  __shared__ __align__(16) unsigned short xs[VPB][K1 + 8];
  __shared__ __align__(16) unsigned short hs[VPB][HID + 8];
  __shared__ int offs[3][VPB + 1];
  __shared__ int codesL[CAPT];

  const int tid = threadIdx.x;
  const int l = tid & 63;
  const int wv = tid >> 6;
  const int b0 = blockIdx.x * VPB;

  if (wv < 6) {
    const int T = wv >> 1, w = wv & 1;
    const int* seg = (T == 0) ? diag_seg : (T == 1) ? proc_seg : med_seg;
    const int n = (T == 0) ? ND : (T == 1) ? NP : NM;
    const int r = lb_wave(seg, n, b0 + (w ? VPB : 0), l);
    if (l == 0) offs[T][w ? VPB : 0] = r;
  }
  __syncthreads();

  const int sD = offs[0][0], cntD = offs[0][VPB] - sD;
  const int sP = offs[1][0], cntP = offs[1][VPB] - sP;
  const int sM = offs[2][0], cntM = offs[2][VPB] - sM;
  const bool stD = (cntD <= CAPD), stP = (cntP <= CAPP), stM = (cntM <= CAPM);

  if (tid < 3 * (VPB - 1)) {
    const int T = tid / (VPB - 1), idx = tid - T * (VPB - 1) + 1;
    offs[T][idx] = offs[T][VPB];
  }
  if (stD) for (int i = tid; i < cntD; i += NTHR) codesL[i] = diag_codes[sD + i];
  if (stP) for (int i = tid; i < cntP; i += NTHR) codesL[CAPD + i] = proc_codes[sP + i];
  if (stM) for (int i = tid; i < cntM; i += NTHR) codesL[CAPD + CAPP + i] = med_codes[sM + i];
  __syncthreads();

#define MARK(Tidx, STAGED, CNT, SBASE, SEGG, NT)                                 \
  if (STAGED) {                                                                  \
    for (int i = tid; i < CNT; i += NTHR) {                                      \
      const int v1 = SEGG[SBASE + i];                                            \
      const int v0_ = (i == 0) ? (b0 - 1) : SEGG[SBASE + i - 1];                 \
      int klo = v0_ + 1; if (klo < b0 + 1) klo = b0 + 1;                         \
      int khi = v1;      if (khi > b0 + VPB - 1) khi = b0 + VPB - 1;             \
      for (int k = klo; k <= khi; ++k) offs[Tidx][k - b0] = SBASE + i;           \
    }                                                                            \
  } else if (tid < VPB - 1) {                                                    \
    offs[Tidx][tid + 1] = lb_fast_scalar(SEGG, NT, b0 + tid + 1);                \
  }

  MARK(0, stD, cntD, sD, diag_seg, ND)
  MARK(1, stP, cntP, sP, proc_seg, NP)
  MARK(2, stM, cntM, sM, med_seg,  NM)
#undef MARK
  __syncthreads();

  const int half = tid >> 5;
  const int ln = tid & 31;

#define GATH(T, CODES_G, TBL, STAGED, SGLOB, LBASE)                               \
  {                                                                               \
    const int s_ = offs[T][half], e_ = offs[T][half + 1];                         \
    float a0 = 0.f, a1 = 0.f, a2 = 0.f, a3 = 0.f;                                 \
    int i = s_;                                                                   \
    if (STAGED) {                                                                 \
      const int lb = LBASE - SGLOB;                                               \
      for (; i + 3 < e_; i += 4) {                                                \
        const int c0 = codesL[lb + i],     c1 = codesL[lb + i + 1];               \
        const int c2 = codesL[lb + i + 2], c3 = codesL[lb + i + 3];               \
        const f32x4 t0 = *(const f32x4*)(TBL + (size_t)c0 * EMB + ln * 4);        \
        const f32x4 t1 = *(const f32x4*)(TBL + (size_t)c1 * EMB + ln * 4);        \
        const f32x4 t2 = *(const f32x4*)(TBL + (size_t)c2 * EMB + ln * 4);        \
        const f32x4 t3 = *(const f32x4*)(TBL + (size_t)c3 * EMB + ln * 4);        \
        a0 += (t0[0] + t1[0]) + (t2[0] + t3[0]);                                  \
        a1 += (t0[1] + t1[1]) + (t2[1] + t3[1]);                                  \
        a2 += (t0[2] + t1[2]) + (t2[2] + t3[2]);                                  \
        a3 += (t0[3] + t1[3]) + (t2[3] + t3[3]);                                  \
      }                                                                           \
      for (; i < e_; ++i) {                                                       \
        const int c = codesL[lb + i];                                             \
        const f32x4 t = *(const f32x4*)(TBL + (size_t)c * EMB + ln * 4);          \
        a0 += t[0]; a1 += t[1]; a2 += t[2]; a3 += t[3];                           \
      }                                                                           \
    } else {                                                                      \
      for (; i < e_; ++i) {                                                       \
        const int c = CODES_G[i];                                                 \
        const f32x4 t = *(const f32x4*)(TBL + (size_t)c * EMB + ln * 4);          \
        a0 += t[0]; a1 += t[1]; a2 += t[2]; a3 += t[3];                           \
      }                                                                           \
    }                                                                             \
    const u32 p0 = (u32)f2bf(a0) | ((u32)f2bf(a1) << 16);                         \
    const u32 p1 = (u32)f2bf(a2) | ((u32)f2bf(a3) << 16);                         \
    uint2* d_ = (uint2*)&xs[half][T * EMB + ln * 4];                              \
    *d_ = make_uint2(p0, p1);                                                     \
  }

  GATH(0, diag_codes, diag_table, stD, sD, 0)
  GATH(1, proc_codes, proc_table, stP, sP, CAPD)
  GATH(2, med_codes,  med_table,  stM, sM, CAPD + CAPP)
#undef GATH
  __syncthreads();

  const int jloc = l & 15;
  const int kq = l >> 4;

  if (wv < 4) {
    const int j1 = wv * 16 + jloc;
    f32x4 acc = {0.f, 0.f, 0.f, 0.f};
    s16x8 bf;
    #pragma unroll
    for (int e = 0; e < 8; ++e)
      bf[e] = (short)f2bf(W1[(size_t)(kq * 8 + e) * HID + j1]);
    #pragma unroll
    for (int kt = 0; kt < 12; ++kt) {
      s16x8 nxt;
      if (kt < 11) {
        const int kb = (kt + 1) * 32 + kq * 8;
        #pragma unroll
        for (int e = 0; e < 8; ++e)
          nxt[e] = (short)f2bf(W1[(size_t)(kb + e) * HID + j1]);
      }
      const s16x8 a0 = *(const s16x8*)&xs[jloc][kt * 32 + kq * 8];
      acc = __builtin_amdgcn_mfma_f32_16x16x32_bf16(a0, bf, acc, 0, 0, 0);
      if (kt < 11) bf = nxt;
    }
    const float bias1 = b1[j1];
    #pragma unroll
    for (int r = 0; r < 4; ++r)
      hs[kq * 4 + r][j1] = f2bf(fmaxf(acc[r] + bias1, 0.f));
  }
  __syncthreads();

  for (int t = wv; t < 10; t += 8) {
    const int n = t * 16 + jloc;
    const bool nok = (n < MED);
    s16x8 bw0, bw1;
    #pragma unroll
    for (int e = 0; e < 8; ++e) {
      const int k0 = kq * 8 + e;
      bw0[e] = nok ? (short)f2bf(W2[(size_t)k0 * MED + n])        : (short)0;
      bw1[e] = nok ? (short)f2bf(W2[(size_t)(k0 + 32) * MED + n]) : (short)0;
    }
    f32x4 o0 = {0.f, 0.f, 0.f, 0.f};
    {
      const int ko = kq * 8;
      const s16x8 a00 = *(const s16x8*)&hs[jloc][ko];
      o0 = __builtin_amdgcn_mfma_f32_16x16x32_bf16(a00, bw0, o0, 0, 0, 0);
      const s16x8 a01 = *(const s16x8*)&hs[jloc][ko + 32];
      o0 = __builtin_amdgcn_mfma_f32_16x16x32_bf16(a01, bw1, o0, 0, 0, 0);
    }
    if (nok) {
      const float bias2 = b2[n];
      #pragma unroll
      for (int r = 0; r < 4; ++r) {
        const int row = kq * 4 + r;
        const float z0 = o0[r] + bias2;
        out[(size_t)(b0 + row) * MED + n] = 1.f / (1.f + __expf(-z0));
      }
    }
  }
}

extern "C" void kernel_launch(void* const* d_in, const int* in_sizes, int n_in,
                              void* d_out, int out_size, void* d_ws, size_t ws_size,
                              hipStream_t stream) {
  const int* diag_codes = (const int*)d_in[0];
  const int* diag_seg   = (const int*)d_in[1];
  const int* proc_codes = (const int*)d_in[2];
  const int* proc_seg   = (const int*)d_in[3];
  const int* med_codes  = (const int*)d_in[4];
  const int* med_seg    = (const int*)d_in[5];
  const float* diag_table = (const float*)d_in[6];
  const float* proc_table = (const float*)d_in[7];
  const float* med_table  = (const float*)d_in[8];
  const float* W1 = (const float*)d_in[9];
  const float* b1 = (const float*)d_in[10];
  const float* W2 = (const float*)d_in[11];
  const float* b2 = (const float*)d_in[12];
  float* out = (float*)d_out;

  if (ws_size >= WS_NEED) {
    unsigned char* ws = (unsigned char*)d_ws;
    prep_kernel<<<dim3(PREP_BLOCKS), dim3(256), 0, stream>>>(
        diag_table, proc_table, med_table, W1, W2, ws);
    fused_ehr_v5<<<dim3(NBLK), dim3(NTHR), 0, stream>>>(
        diag_codes, diag_seg, proc_codes, proc_seg, med_codes, med_seg,
        b1, b2, ws, out, in_sizes[0], in_sizes[2], in_sizes[4]);
  } else {
    fused_ehr_fb<<<dim3(NBLK), dim3(NTHR), 0, stream>>>(
        diag_codes, diag_seg, proc_codes, proc_seg, med_codes, med_seg,
        diag_table, proc_table, med_table, W1, b1, W2, b2, out,
        in_sizes[0], in_sizes[2], in_sizes[4]);
  }
}

// Round 6
// 29.371 us; speedup vs baseline: 1.6843x; 1.0340x over previous
//
#include <hip/hip_runtime.h>
#include <hip/hip_bf16.h>

#define NVIS 16384
#define EMB 128
#define HID 64
#define MED 153
#define K1 384
#define VPB 16
#define NTHR 512
#define NBLK (NVIS / VPB)    // 1024 blocks x 512 thr = 4 blocks/CU, 32 waves/CU
#define CAPD 640
#define CAPP 384
#define CAPM 512
#define CAPT (CAPD + CAPP + CAPM)

// ---- d_ws layout (16B-aligned) ----
#define W2F_OFF 0u                      // 10*2*64 frags * 16B = 20480
#define TWD_OFF 20480u                  // 2000*64 f32 = 512000
#define TWP_OFF (20480u + 512000u)      // 532480
#define TWM_OFF (532480u + 384000u)     // 916480: 153*64 f32 = 39168
#define WS_NEED (916480u + 39168u)      // 955648

#define NW2F 1280
#define TW_BLKS_D 500
#define TW_BLKS_P 375
#define TW_BLKS_M 39                    // ceil(153/4)
#define TW_BLKS (TW_BLKS_D + TW_BLKS_P + TW_BLKS_M)   // 914
#define PREP_BLOCKS (TW_BLKS + 5)       // + 5 blocks for W2 frags

typedef float f32x4 __attribute__((ext_vector_type(4)));
typedef short s16x8 __attribute__((ext_vector_type(8)));
typedef unsigned int u32;
typedef unsigned int u32x4 __attribute__((ext_vector_type(4)));

__device__ __forceinline__ unsigned short f2bf(float f) {
  union { float f; unsigned u; } v; v.f = f;
  unsigned r = v.u + 0x7FFFu + ((v.u >> 16) & 1u);   // round-to-nearest-even
  return (unsigned short)(r >> 16);
}

__device__ __forceinline__ int lb_scalar(const int* __restrict__ a, int lo, int hi, int key) {
  while (lo < hi) {
    int mid = (lo + hi) >> 1;
    if (a[mid] < key) lo = mid + 1; else hi = mid;
  }
  return lo;
}

__device__ __forceinline__ int lb_fast_scalar(const int* __restrict__ a, int n, int key) {
  long long g = ((long long)key * (long long)n) >> 14;
  int L = (int)g - 3072, R = (int)g + 3072;
  if (L < 0) L = 0;
  if (R > n) R = n;
  const bool ok = (L == 0 || a[L - 1] < key) && (R == n || a[R] >= key);
  if (!ok) { L = 0; R = n; }
  return lb_scalar(a, L, R, key);
}

// wave-parallel lower_bound: all 64 lanes participate, returns uniform result.
__device__ __forceinline__ int lb_wave(const int* __restrict__ a, int n, int key, int lane) {
  long long g = ((long long)key * (long long)n) >> 14;
  int L = (int)g - 3072, R = (int)g + 3072;
  if (L < 0) L = 0;
  if (R > n) R = n;
  const bool ok = (L == 0 || a[L - 1] < key) && (R == n || a[R] >= key);
  if (!ok) { L = 0; R = n; }
  int lo = L - 1, hi = R;
  while (hi - lo > 1) {
    const int width = hi - lo - 1;
    const int p = lo + 1 + (int)(((long long)width * lane) >> 6);
    const bool lt = a[p] < key;
    const unsigned long long m = __ballot(lt);
    const int t = m ? (63 - __builtin_clzll(m)) : -1;
    const int nlo = (t >= 0) ? lo + 1 + (int)(((long long)width * t) >> 6) : lo;
    const int nhi = (t < 63) ? lo + 1 + (int)(((long long)width * (t + 1)) >> 6) : hi;
    lo = nlo; hi = nhi;
  }
  return hi;
}

// ============== prep: TW = table @ W1_slice (f32) + W2 fragment-order bf16 ==============
__global__ __launch_bounds__(256, 4) void prep_kernel(
    const float* __restrict__ dT, const float* __restrict__ pT, const float* __restrict__ mT,
    const float* __restrict__ W1, const float* __restrict__ W2,
    unsigned char* __restrict__ ws)
{
  __shared__ float w1L[128 * 64];   // 32 KB: W1 slice for this table
  const int blk = blockIdx.x;
  const int tid = threadIdx.x;

  if (blk < TW_BLKS) {
    const float* tbl; int rows, r0, koff; unsigned char* dst;
    if (blk < TW_BLKS_D)                 { tbl = dT; rows = 2000; r0 = blk * 4;                koff = 0;   dst = ws + TWD_OFF; }
    else if (blk < TW_BLKS_D + TW_BLKS_P){ tbl = pT; rows = 1500; r0 = (blk - TW_BLKS_D) * 4;  koff = 128; dst = ws + TWP_OFF; }
    else                                 { tbl = mT; rows = 153;  r0 = (blk - TW_BLKS_D - TW_BLKS_P) * 4; koff = 256; dst = ws + TWM_OFF; }
    // stage W1[koff:koff+128][0:64] into LDS (vectorized, coalesced)
    for (int i = tid; i < 128 * 64 / 4; i += 256)
      *(f32x4*)&w1L[i * 4] = *(const f32x4*)&W1[(size_t)koff * HID + i * 4];
    __syncthreads();

    const int r = r0 + (tid >> 6);
    const int j = tid & 63;
    if (r < rows) {
      float acc = 0.f;
      #pragma unroll 8
      for (int k4 = 0; k4 < 32; ++k4) {
        const f32x4 t = *(const f32x4*)(tbl + (size_t)r * EMB + k4 * 4);
        acc += t[0] * w1L[(k4 * 4 + 0) * 64 + j] + t[1] * w1L[(k4 * 4 + 1) * 64 + j]
             + t[2] * w1L[(k4 * 4 + 2) * 64 + j] + t[3] * w1L[(k4 * 4 + 3) * 64 + j];
      }
      *(float*)(dst + ((size_t)r * HID + j) * 4) = acc;
    }
  } else {
    // W2 fragments: (tile*2+kh)*64 + lane -> 16B each
    const int t = (blk - TW_BLKS) * 256 + tid;
    if (t < NW2F) {
      const int lane = t & 63, tk = t >> 6;
      const int kh = tk & 1, tile = tk >> 1;
      const int n = tile * 16 + (lane & 15);
      const int k0 = kh * 32 + (lane >> 4) * 8;
      unsigned short e0[8];
      #pragma unroll
      for (int e = 0; e < 8; ++e)
        e0[e] = (n < MED) ? f2bf(W2[(size_t)(k0 + e) * MED + n]) : (unsigned short)0;
      u32x4 o;
      o[0] = (u32)e0[0] | ((u32)e0[1] << 16);
      o[1] = (u32)e0[2] | ((u32)e0[3] << 16);
      o[2] = (u32)e0[4] | ((u32)e0[5] << 16);
      o[3] = (u32)e0[6] | ((u32)e0[7] << 16);
      *(u32x4*)(ws + W2F_OFF + (size_t)t * 16) = o;
    }
  }
}

// ============== main: segment-sum of TW rows -> relu -> GEMM2 -> sigmoid ==============
__global__ __launch_bounds__(NTHR, 8) void fused_ehr_v6(
    const int* __restrict__ diag_codes, const int* __restrict__ diag_seg,
    const int* __restrict__ proc_codes, const int* __restrict__ proc_seg,
    const int* __restrict__ med_codes,  const int* __restrict__ med_seg,
    const float* __restrict__ b1, const float* __restrict__ b2,
    const unsigned char* __restrict__ ws,
    float* __restrict__ out, int ND, int NP, int NM)
{
  __shared__ __align__(16) unsigned short hs[VPB][HID + 8];  // 2304 B
  __shared__ int offs[3][VPB + 1];
  __shared__ int codesL[CAPT];                               // 6144 B

  const int tid = threadIdx.x;
  const int l = tid & 63;
  const int wv = tid >> 6;
  const int b0 = blockIdx.x * VPB;

  // ---- 6 end-boundary searches, one per wave, 64-ary ----
  if (wv < 6) {
    const int T = wv >> 1, w = wv & 1;
    const int* seg = (T == 0) ? diag_seg : (T == 1) ? proc_seg : med_seg;
    const int n = (T == 0) ? ND : (T == 1) ? NP : NM;
    const int r = lb_wave(seg, n, b0 + (w ? VPB : 0), l);
    if (l == 0) offs[T][w ? VPB : 0] = r;
  }
  __syncthreads();

  const int sD = offs[0][0], cntD = offs[0][VPB] - sD;
  const int sP = offs[1][0], cntP = offs[1][VPB] - sP;
  const int sM = offs[2][0], cntM = offs[2][VPB] - sM;
  const bool stD = (cntD <= CAPD), stP = (cntP <= CAPP), stM = (cntM <= CAPM);

  if (tid < 3 * (VPB - 1)) {
    const int T = tid / (VPB - 1), idx = tid - T * (VPB - 1) + 1;
    offs[T][idx] = offs[T][VPB];
  }
  if (stD) for (int i = tid; i < cntD; i += NTHR) codesL[i] = diag_codes[sD + i];
  if (stP) for (int i = tid; i < cntP; i += NTHR) codesL[CAPD + i] = proc_codes[sP + i];
  if (stM) for (int i = tid; i < cntM; i += NTHR) codesL[CAPD + CAPP + i] = med_codes[sM + i];
  __syncthreads();

#define MARK(Tidx, STAGED, CNT, SBASE, SEGG, NT)                                 \
  if (STAGED) {                                                                  \
    for (int i = tid; i < CNT; i += NTHR) {                                      \
      const int v1 = SEGG[SBASE + i];                                            \
      const int v0_ = (i == 0) ? (b0 - 1) : SEGG[SBASE + i - 1];                 \
      int klo = v0_ + 1; if (klo < b0 + 1) klo = b0 + 1;                         \
      int khi = v1;      if (khi > b0 + VPB - 1) khi = b0 + VPB - 1;             \
      for (int k = klo; k <= khi; ++k) offs[Tidx][k - b0] = SBASE + i;           \
    }                                                                            \
  } else if (tid < VPB - 1) {                                                    \
    offs[Tidx][tid + 1] = lb_fast_scalar(SEGG, NT, b0 + tid + 1);                \
  }

  MARK(0, stD, cntD, sD, diag_seg, ND)
  MARK(1, stP, cntP, sP, proc_seg, NP)
  MARK(2, stM, cntM, sM, med_seg,  NM)
#undef MARK
  __syncthreads();

  // ---- gather: one 32-lane half-wave per visit; 256B f32 TW rows ----
  // 16 lanes cover one row (f32x4 each); two 16-lane groups take even/odd codes.
  const int half = tid >> 5;        // visit 0..15
  const int ln = tid & 31;
  const int pr = ln >> 4;           // code parity
  const int dd = ln & 15;           // f32x4 chunk: dims dd*4 .. dd*4+3
  const float* twD = (const float*)(ws + TWD_OFF);
  const float* twP = (const float*)(ws + TWP_OFF);
  const float* twM = (const float*)(ws + TWM_OFF);

  float a0 = 0.f, a1 = 0.f, a2 = 0.f, a3 = 0.f;

#define GTW(T, CODES_G, TW, STAGED, SGLOB, LBASE)                                 \
  {                                                                               \
    const int s_ = offs[T][half], e_ = offs[T][half + 1];                         \
    int i = s_;                                                                   \
    if (STAGED) {                                                                 \
      const int lb = LBASE - SGLOB;                                               \
      for (; i + 7 < e_; i += 8) {                                                \
        const int c0 = codesL[lb + i + pr],     c1 = codesL[lb + i + 2 + pr];     \
        const int c2 = codesL[lb + i + 4 + pr], c3 = codesL[lb + i + 6 + pr];     \
        const f32x4 t0 = *(const f32x4*)(TW + (size_t)c0 * HID + dd * 4);         \
        const f32x4 t1 = *(const f32x4*)(TW + (size_t)c1 * HID + dd * 4);         \
        const f32x4 t2 = *(const f32x4*)(TW + (size_t)c2 * HID + dd * 4);         \
        const f32x4 t3 = *(const f32x4*)(TW + (size_t)c3 * HID + dd * 4);         \
        a0 += (t0[0] + t1[0]) + (t2[0] + t3[0]);                                  \
        a1 += (t0[1] + t1[1]) + (t2[1] + t3[1]);                                  \
        a2 += (t0[2] + t1[2]) + (t2[2] + t3[2]);                                  \
        a3 += (t0[3] + t1[3]) + (t2[3] + t3[3]);                                  \
      }                                                                           \
      for (; i + pr < e_; i += 2) {                                               \
        const int c = codesL[lb + i + pr];                                        \
        const f32x4 t = *(const f32x4*)(TW + (size_t)c * HID + dd * 4);           \
        a0 += t[0]; a1 += t[1]; a2 += t[2]; a3 += t[3];                           \
      }                                                                           \
    } else {                                                                      \
      for (; i + pr < e_; i += 2) {                                               \
        const int c = CODES_G[i + pr];                                            \
        const f32x4 t = *(const f32x4*)(TW + (size_t)c * HID + dd * 4);           \
        a0 += t[0]; a1 += t[1]; a2 += t[2]; a3 += t[3];                           \
      }                                                                           \
    }                                                                             \
  }

  GTW(0, diag_codes, twD, stD, sD, 0)
  GTW(1, proc_codes, twP, stP, sP, CAPD)
  GTW(2, med_codes,  twM, stM, sM, CAPD + CAPP)
#undef GTW

  // combine code-parity partials, add bias, relu, pack to bf16 h row
  a0 += __shfl_xor(a0, 16); a1 += __shfl_xor(a1, 16);
  a2 += __shfl_xor(a2, 16); a3 += __shfl_xor(a3, 16);
  if (pr == 0) {
    const f32x4 bb = *(const f32x4*)(b1 + dd * 4);
    const u32 p0 = (u32)f2bf(fmaxf(a0 + bb[0], 0.f)) | ((u32)f2bf(fmaxf(a1 + bb[1], 0.f)) << 16);
    const u32 p1 = (u32)f2bf(fmaxf(a2 + bb[2], 0.f)) | ((u32)f2bf(fmaxf(a3 + bb[3], 0.f)) << 16);
    *(uint2*)&hs[half][dd * 4] = make_uint2(p0, p1);
  }
  __syncthreads();

  // ---- GEMM2 (all 8 waves): out[16][153] = sigmoid(h @ W2 + b2); 10 N-tiles ----
  // A frag: row=l&15, k=(l>>4)*8+e.  B from pre-swizzled w2f.  D: col=l&15, row=(l>>4)*4+reg.
  const int jloc = l & 15;
  const int kq = l >> 4;
  const s16x8* w2f = (const s16x8*)(ws + W2F_OFF);

  for (int t = wv; t < 10; t += 8) {
    const int n = t * 16 + jloc;
    const bool nok = (n < MED);
    const s16x8 bw0 = w2f[(t * 2 + 0) * 64 + l];
    const s16x8 bw1 = w2f[(t * 2 + 1) * 64 + l];
    f32x4 o0 = {0.f, 0.f, 0.f, 0.f};
    {
      const int ko = kq * 8;
      const s16x8 a00 = *(const s16x8*)&hs[jloc][ko];
      o0 = __builtin_amdgcn_mfma_f32_16x16x32_bf16(a00, bw0, o0, 0, 0, 0);
      const s16x8 a01 = *(const s16x8*)&hs[jloc][ko + 32];
      o0 = __builtin_amdgcn_mfma_f32_16x16x32_bf16(a01, bw1, o0, 0, 0, 0);
    }
    if (nok) {
      const float bias2 = b2[n];
      #pragma unroll
      for (int r = 0; r < 4; ++r) {
        const int row = kq * 4 + r;
        const float z0 = o0[r] + bias2;
        out[(size_t)(b0 + row) * MED + n] = 1.f / (1.f + __expf(-z0));
      }
    }
  }
}

// ============== fallback (round-4 kernel, f32 tables, no ws) ==============
__global__ __launch_bounds__(NTHR, 8) void fused_ehr_fb(
    const int* __restrict__ diag_codes, const int* __restrict__ diag_seg,
    const int* __restrict__ proc_codes, const int* __restrict__ proc_seg,
    const int* __restrict__ med_codes,  const int* __restrict__ med_seg,
    const float* __restrict__ diag_table, const float* __restrict__ proc_table,
    const float* __restrict__ med_table,
    const float* __restrict__ W1, const float* __restrict__ b1,
    const float* __restrict__ W2, const float* __restrict__ b2,
    float* __restrict__ out, int ND, int NP, int NM)
{
  __shared__ __align__(16) unsigned short xs[VPB][K1 + 8];
  __shared__ __align__(16) unsigned short hs[VPB][HID + 8];
  __shared__ int offs[3][VPB + 1];
  __shared__ int codesL[CAPT];

  const int tid = threadIdx.x;
  const int l = tid & 63;
  const int wv = tid >> 6;
  const int b0 = blockIdx.x * VPB;

  if (wv < 6) {
    const int T = wv >> 1, w = wv & 1;
    const int* seg = (T == 0) ? diag_seg : (T == 1) ? proc_seg : med_seg;
    const int n = (T == 0) ? ND : (T == 1) ? NP : NM;
    const int r = lb_wave(seg, n, b0 + (w ? VPB : 0), l);
    if (l == 0) offs[T][w ? VPB : 0] = r;
  }
  __syncthreads();

  const int sD = offs[0][0], cntD = offs[0][VPB] - sD;
  const int sP = offs[1][0], cntP = offs[1][VPB] - sP;
  const int sM = offs[2][0], cntM = offs[2][VPB] - sM;
  const bool stD = (cntD <= CAPD), stP = (cntP <= CAPP), stM = (cntM <= CAPM);

  if (tid < 3 * (VPB - 1)) {
    const int T = tid / (VPB - 1), idx = tid - T * (VPB - 1) + 1;
    offs[T][idx] = offs[T][VPB];
  }
  if (stD) for (int i = tid; i < cntD; i += NTHR) codesL[i] = diag_codes[sD + i];
  if (stP) for (int i = tid; i < cntP; i += NTHR) codesL[CAPD + i] = proc_codes[sP + i];
  if (stM) for (int i = tid; i < cntM; i += NTHR) codesL[CAPD + CAPP + i] = med_codes[sM + i];
  __syncthreads();

#define MARK(Tidx, STAGED, CNT, SBASE, SEGG, NT)                                 \
  if (STAGED) {                                                                  \
    for (int i = tid; i < CNT; i += NTHR) {                                      \
      const int v1 = SEGG[SBASE + i];                                            \
      const int v0_ = (i == 0) ? (b0 - 1) : SEGG[SBASE + i - 1];                 \
      int klo = v0_ + 1; if (klo < b0 + 1) klo = b0 + 1;                         \
      int khi = v1;      if (khi > b0 + VPB - 1) khi = b0 + VPB - 1;             \
      for (int k = klo; k <= khi; ++k) offs[Tidx][k - b0] = SBASE + i;           \
    }                                                                            \
  } else if (tid < VPB - 1) {                                                    \
    offs[Tidx][tid + 1] = lb_fast_scalar(SEGG, NT, b0 + tid + 1);                \
  }

  MARK(0, stD, cntD, sD, diag_seg, ND)
  MARK(1, stP, cntP, sP, proc_seg, NP)
  MARK(2, stM, cntM, sM, med_seg,  NM)
#undef MARK
  __syncthreads();

  const int half = tid >> 5;
  const int ln = tid & 31;

#define GATH(T, CODES_G, TBL, STAGED, SGLOB, LBASE)                               \
  {                                                                               \
    const int s_ = offs[T][half], e_ = offs[T][half + 1];                         \
    float a0 = 0.f, a1 = 0.f, a2 = 0.f, a3 = 0.f;                                 \
    int i = s_;                                                                   \
    if (STAGED) {                                                                 \
      const int lb = LBASE - SGLOB;                                               \
      for (; i + 3 < e_; i += 4) {                                                \
        const int c0 = codesL[lb + i],     c1 = codesL[lb + i + 1];               \
        const int c2 = codesL[lb + i + 2], c3 = codesL[lb + i + 3];               \
        const f32x4 t0 = *(const f32x4*)(TBL + (size_t)c0 * EMB + ln * 4);        \
        const f32x4 t1 = *(const f32x4*)(TBL + (size_t)c1 * EMB + ln * 4);        \
        const f32x4 t2 = *(const f32x4*)(TBL + (size_t)c2 * EMB + ln * 4);        \
        const f32x4 t3 = *(const f32x4*)(TBL + (size_t)c3 * EMB + ln * 4);        \
        a0 += (t0[0] + t1[0]) + (t2[0] + t3[0]);                                  \
        a1 += (t0[1] + t1[1]) + (t2[1] + t3[1]);                                  \
        a2 += (t0[2] + t1[2]) + (t2[2] + t3[2]);                                  \
        a3 += (t0[3] + t1[3]) + (t2[3] + t3[3]);                                  \
      }                                                                           \
      for (; i < e_; ++i) {                                                       \
        const int c = codesL[lb + i];                                             \
        const f32x4 t = *(const f32x4*)(TBL + (size_t)c * EMB + ln * 4);          \
        a0 += t[0]; a1 += t[1]; a2 += t[2]; a3 += t[3];                           \
      }                                                                           \
    } else {                                                                      \
      for (; i < e_; ++i) {                                                       \
        const int c = CODES_G[i];                                                 \
        const f32x4 t = *(const f32x4*)(TBL + (size_t)c * EMB + ln * 4);          \
        a0 += t[0]; a1 += t[1]; a2 += t[2]; a3 += t[3];                           \
      }                                                                           \
    }                                                                             \
    const u32 p0 = (u32)f2bf(a0) | ((u32)f2bf(a1) << 16);                         \
    const u32 p1 = (u32)f2bf(a2) | ((u32)f2bf(a3) << 16);                         \
    uint2* d_ = (uint2*)&xs[half][T * EMB + ln * 4];                              \
    *d_ = make_uint2(p0, p1);                                                     \
  }

  GATH(0, diag_codes, diag_table, stD, sD, 0)
  GATH(1, proc_codes, proc_table, stP, sP, CAPD)
  GATH(2, med_codes,  med_table,  stM, sM, CAPD + CAPP)
#undef GATH
  __syncthreads();

  const int jloc = l & 15;
  const int kq = l >> 4;

  if (wv < 4) {
    const int j1 = wv * 16 + jloc;
    f32x4 acc = {0.f, 0.f, 0.f, 0.f};
    s16x8 bf;
    #pragma unroll
    for (int e = 0; e < 8; ++e)
      bf[e] = (short)f2bf(W1[(size_t)(kq * 8 + e) * HID + j1]);
    #pragma unroll
    for (int kt = 0; kt < 12; ++kt) {
      s16x8 nxt;
      if (kt < 11) {
        const int kb = (kt + 1) * 32 + kq * 8;
        #pragma unroll
        for (int e = 0; e < 8; ++e)
          nxt[e] = (short)f2bf(W1[(size_t)(kb + e) * HID + j1]);
      }
      const s16x8 a0 = *(const s16x8*)&xs[jloc][kt * 32 + kq * 8];
      acc = __builtin_amdgcn_mfma_f32_16x16x32_bf16(a0, bf, acc, 0, 0, 0);
      if (kt < 11) bf = nxt;
    }
    const float bias1 = b1[j1];
    #pragma unroll
    for (int r = 0; r < 4; ++r)
      hs[kq * 4 + r][j1] = f2bf(fmaxf(acc[r] + bias1, 0.f));
  }
  __syncthreads();

  for (int t = wv; t < 10; t += 8) {
    const int n = t * 16 + jloc;
    const bool nok = (n < MED);
    s16x8 bw0, bw1;
    #pragma unroll
    for (int e = 0; e < 8; ++e) {
      const int k0 = kq * 8 + e;
      bw0[e] = nok ? (short)f2bf(W2[(size_t)k0 * MED + n])        : (short)0;
      bw1[e] = nok ? (short)f2bf(W2[(size_t)(k0 + 32) * MED + n]) : (short)0;
    }
    f32x4 o0 = {0.f, 0.f, 0.f, 0.f};
    {
      const int ko = kq * 8;
      const s16x8 a00 = *(const s16x8*)&hs[jloc][ko];
      o0 = __builtin_amdgcn_mfma_f32_16x16x32_bf16(a00, bw0, o0, 0, 0, 0);
      const s16x8 a01 = *(const s16x8*)&hs[jloc][ko + 32];
      o0 = __builtin_amdgcn_mfma_f32_16x16x32_bf16(a01, bw1, o0, 0, 0, 0);
    }
    if (nok) {
      const float bias2 = b2[n];
      #pragma unroll
      for (int r = 0; r < 4; ++r) {
        const int row = kq * 4 + r;
        const float z0 = o0[r] + bias2;
        out[(size_t)(b0 + row) * MED + n] = 1.f / (1.f + __expf(-z0));
      }
    }
  }
}

extern "C" void kernel_launch(void* const* d_in, const int* in_sizes, int n_in,
                              void* d_out, int out_size, void* d_ws, size_t ws_size,
                              hipStream_t stream) {
  const int* diag_codes = (const int*)d_in[0];
  const int* diag_seg   = (const int*)d_in[1];
  const int* proc_codes = (const int*)d_in[2];
  const int* proc_seg   = (const int*)d_in[3];
  const int* med_codes  = (const int*)d_in[4];
  const int* med_seg    = (const int*)d_in[5];
  const float* diag_table = (const float*)d_in[6];
  const float* proc_table = (const float*)d_in[7];
  const float* med_table  = (const float*)d_in[8];
  const float* W1 = (const float*)d_in[9];
  const float* b1 = (const float*)d_in[10];
  const float* W2 = (const float*)d_in[11];
  const float* b2 = (const float*)d_in[12];
  float* out = (float*)d_out;

  if (ws_size >= WS_NEED) {
    unsigned char* ws = (unsigned char*)d_ws;
    prep_kernel<<<dim3(PREP_BLOCKS), dim3(256), 0, stream>>>(
        diag_table, proc_table, med_table, W1, W2, ws);
    fused_ehr_v6<<<dim3(NBLK), dim3(NTHR), 0, stream>>>(
        diag_codes, diag_seg, proc_codes, proc_seg, med_codes, med_seg,
        b1, b2, ws, out, in_sizes[0], in_sizes[2], in_sizes[4]);
  } else {
    fused_ehr_fb<<<dim3(NBLK), dim3(NTHR), 0, stream>>>(
        diag_codes, diag_seg, proc_codes, proc_seg, med_codes, med_seg,
        diag_table, proc_table, med_table, W1, b1, W2, b2, out,
        in_sizes[0], in_sizes[2], in_sizes[4]);
  }
}

// Round 7
// 25.563 us; speedup vs baseline: 1.9353x; 1.1490x over previous
//
#include <hip/hip_runtime.h>
#include <hip/hip_bf16.h>

#define NVIS 16384
#define EMB 128
#define HID 64
#define MED 153
#define K1 384
#define VPB 16
#define NTHR 512
#define NBLK (NVIS / VPB)    // 1024 blocks x 512 thr = 4 blocks/CU, 32 waves/CU
#define CAPT 1536            // combined staged-code capacity per block

// ---- d_ws layout (16B aligned) ----
#define W2F_OFF  0u                         // 10*2*64 frags * 16B = 20480
#define OFFS_OFF 20480u                     // 3 * 16388 * 4 = 196656
#define OFFS_STRIDE 16388
#define TW_OFF   (20480u + 196656u)         // 217136; 3653 rows * 128 B = 467584
#define WS_NEED  (217136u + 467584u)        // 684720

#define ROWS_D 2000
#define ROWS_P 1500
#define ROWS_M 153
#define TBASE_D 0
#define TBASE_P 2000
#define TBASE_M 3500

#define SRCH_BLKS 193                        // ceil(3*16385/256)
#define TWB_D 500
#define TWB_P 375
#define TWB_M 39
#define TWB_ALL (TWB_D + TWB_P + TWB_M)      // 914
#define NW2F 1280
#define PREP_BLKS (SRCH_BLKS + TWB_ALL + 5)  // 1112

typedef float f32x4 __attribute__((ext_vector_type(4)));
typedef short s16x8 __attribute__((ext_vector_type(8)));
typedef unsigned int u32;
typedef unsigned int u32x4 __attribute__((ext_vector_type(4)));

__device__ __forceinline__ unsigned short f2bf(float f) {
  union { float f; unsigned u; } v; v.f = f;
  unsigned r = v.u + 0x7FFFu + ((v.u >> 16) & 1u);   // round-to-nearest-even
  return (unsigned short)(r >> 16);
}

// unpack 8 bf16 from u32x4, masked-fma into A[8]
__device__ __forceinline__ void acc8m(u32x4 t, float m, float* A) {
  union { unsigned u; float f; } c;
  c.u = t[0] << 16;          A[0] = fmaf(m, c.f, A[0]);
  c.u = t[0] & 0xFFFF0000u;  A[1] = fmaf(m, c.f, A[1]);
  c.u = t[1] << 16;          A[2] = fmaf(m, c.f, A[2]);
  c.u = t[1] & 0xFFFF0000u;  A[3] = fmaf(m, c.f, A[3]);
  c.u = t[2] << 16;          A[4] = fmaf(m, c.f, A[4]);
  c.u = t[2] & 0xFFFF0000u;  A[5] = fmaf(m, c.f, A[5]);
  c.u = t[3] << 16;          A[6] = fmaf(m, c.f, A[6]);
  c.u = t[3] & 0xFFFF0000u;  A[7] = fmaf(m, c.f, A[7]);
}

__device__ __forceinline__ int lb_scalar(const int* __restrict__ a, int lo, int hi, int key) {
  while (lo < hi) {
    int mid = (lo + hi) >> 1;
    if (a[mid] < key) lo = mid + 1; else hi = mid;
  }
  return lo;
}

__device__ __forceinline__ int lb_fast_scalar(const int* __restrict__ a, int n, int key) {
  long long g = ((long long)key * (long long)n) >> 14;
  int L = (int)g - 3072, R = (int)g + 3072;
  if (L < 0) L = 0;
  if (R > n) R = n;
  const bool ok = (L == 0 || a[L - 1] < key) && (R == n || a[R] >= key);
  if (!ok) { L = 0; R = n; }
  return lb_scalar(a, L, R, key);
}

// wave-parallel lower_bound (fallback kernel only)
__device__ __forceinline__ int lb_wave(const int* __restrict__ a, int n, int key, int lane) {
  long long g = ((long long)key * (long long)n) >> 14;
  int L = (int)g - 3072, R = (int)g + 3072;
  if (L < 0) L = 0;
  if (R > n) R = n;
  const bool ok = (L == 0 || a[L - 1] < key) && (R == n || a[R] >= key);
  if (!ok) { L = 0; R = n; }
  int lo = L - 1, hi = R;
  while (hi - lo > 1) {
    const int width = hi - lo - 1;
    const int p = lo + 1 + (int)(((long long)width * lane) >> 6);
    const bool lt = a[p] < key;
    const unsigned long long m = __ballot(lt);
    const int t = m ? (63 - __builtin_clzll(m)) : -1;
    const int nlo = (t >= 0) ? lo + 1 + (int)(((long long)width * t) >> 6) : lo;
    const int nhi = (t < 63) ? lo + 1 + (int)(((long long)width * (t + 1)) >> 6) : hi;
    lo = nlo; hi = nhi;
  }
  return hi;
}

// ============== prep: boundaries + TW bf16 + W2 frags ==============
__global__ __launch_bounds__(256, 4) void prep_kernel(
    const int* __restrict__ diag_seg, const int* __restrict__ proc_seg,
    const int* __restrict__ med_seg,
    const float* __restrict__ dT, const float* __restrict__ pT, const float* __restrict__ mT,
    const float* __restrict__ W1, const float* __restrict__ W2,
    unsigned char* __restrict__ ws, int ND, int NP, int NM)
{
  __shared__ float w1L[128 * 64];
  const int blk = blockIdx.x;
  const int tid = threadIdx.x;

  if (blk < SRCH_BLKS) {
    // all 3*16385 segment boundaries
    const int t = blk * 256 + tid;
    if (t < 3 * 16385) {
      const int T = t / 16385, k = t - T * 16385;
      const int* seg = (T == 0) ? diag_seg : (T == 1) ? proc_seg : med_seg;
      const int n = (T == 0) ? ND : (T == 1) ? NP : NM;
      ((int*)(ws + OFFS_OFF))[T * OFFS_STRIDE + k] = lb_fast_scalar(seg, n, k);
    }
  } else if (blk < SRCH_BLKS + TWB_ALL) {
    const int blk2 = blk - SRCH_BLKS;
    const float* tbl; int rows, r0, koff, tBase;
    if (blk2 < TWB_D)                { tbl = dT; rows = ROWS_D; r0 = blk2 * 4;            koff = 0;   tBase = TBASE_D; }
    else if (blk2 < TWB_D + TWB_P)   { tbl = pT; rows = ROWS_P; r0 = (blk2 - TWB_D) * 4;  koff = 128; tBase = TBASE_P; }
    else                             { tbl = mT; rows = ROWS_M; r0 = (blk2 - TWB_D - TWB_P) * 4; koff = 256; tBase = TBASE_M; }
    for (int i = tid; i < 128 * 64 / 4; i += 256)
      *(f32x4*)&w1L[i * 4] = *(const f32x4*)&W1[(size_t)koff * HID + i * 4];
    __syncthreads();
    const int r = r0 + (tid >> 6);
    const int j = tid & 63;
    if (r < rows) {
      float acc = 0.f;
      #pragma unroll 8
      for (int k4 = 0; k4 < 32; ++k4) {
        const f32x4 t = *(const f32x4*)(tbl + (size_t)r * EMB + k4 * 4);
        acc += t[0] * w1L[(k4 * 4 + 0) * 64 + j] + t[1] * w1L[(k4 * 4 + 1) * 64 + j]
             + t[2] * w1L[(k4 * 4 + 2) * 64 + j] + t[3] * w1L[(k4 * 4 + 3) * 64 + j];
      }
      *(unsigned short*)(ws + TW_OFF + (size_t)(tBase + r) * 128 + j * 2) = f2bf(acc);
    }
  } else {
    const int t = (blk - SRCH_BLKS - TWB_ALL) * 256 + tid;
    if (t < NW2F) {
      const int lane = t & 63, tk = t >> 6;
      const int kh = tk & 1, tile = tk >> 1;
      const int n = tile * 16 + (lane & 15);
      const int k0 = kh * 32 + (lane >> 4) * 8;
      unsigned short e0[8];
      #pragma unroll
      for (int e = 0; e < 8; ++e)
        e0[e] = (n < MED) ? f2bf(W2[(size_t)(k0 + e) * MED + n]) : (unsigned short)0;
      u32x4 o;
      o[0] = (u32)e0[0] | ((u32)e0[1] << 16);
      o[1] = (u32)e0[2] | ((u32)e0[3] << 16);
      o[2] = (u32)e0[4] | ((u32)e0[5] << 16);
      o[3] = (u32)e0[6] | ((u32)e0[7] << 16);
      *(u32x4*)(ws + W2F_OFF + (size_t)t * 16) = o;
    }
  }
}

// ============== main: merged bf16-TW gather -> relu -> GEMM2 -> sigmoid ==============
__global__ __launch_bounds__(NTHR, 8) void fused_ehr_v7(
    const int* __restrict__ diag_codes, const int* __restrict__ proc_codes,
    const int* __restrict__ med_codes,
    const float* __restrict__ b1, const float* __restrict__ b2,
    const unsigned char* __restrict__ ws,
    float* __restrict__ out)
{
  __shared__ __align__(16) unsigned short hs[VPB][HID + 8];  // 2304 B
  __shared__ int offsL[3][17];
  __shared__ int csL[17];
  __shared__ int twoffL[CAPT];                               // 6144 B

  const int tid = threadIdx.x;
  const int l = tid & 63;
  const int wv = tid >> 6;
  const int b0 = blockIdx.x * VPB;
  const int* offsAll = (const int*)(ws + OFFS_OFF);

  // ---- load precomputed boundaries (coalesced, 51 ints) ----
  if (tid < 51) {
    const int T = tid / 17, idx = tid - T * 17;
    offsL[T][idx] = offsAll[T * OFFS_STRIDE + b0 + idx];
  }
  __syncthreads();
  if (tid < 17) {
    csL[tid] = (offsL[0][tid] - offsL[0][0]) + (offsL[1][tid] - offsL[1][0])
             + (offsL[2][tid] - offsL[2][0]);
  }
  __syncthreads();

  const int total = csL[16];
  const bool stAll = (total <= CAPT);

  // ---- stage merged, visit-grouped TW byte-offsets ----
  if (stAll) {
#define STAGE(T, CG, TBASE)                                                     \
    {                                                                           \
      const int sT = offsL[T][0], cnt = offsL[T][16] - sT;                      \
      for (int i = tid; i < cnt; i += NTHR) {                                   \
        const int key = sT + i;                                                 \
        int lo = 0, hi = 16;                                                    \
        _Pragma("unroll")                                                       \
        for (int it = 0; it < 4; ++it) {                                        \
          const int m = (lo + hi) >> 1;                                         \
          if (offsL[T][m] <= key) lo = m; else hi = m;                          \
        }                                                                       \
        const int within = key - offsL[T][lo];                                  \
        int prior = 0;                                                          \
        if (T >= 1) prior += offsL[0][lo + 1] - offsL[0][lo];                   \
        if (T == 2) prior += offsL[1][lo + 1] - offsL[1][lo];                   \
        twoffL[csL[lo] + prior + within] = (TBASE + CG[key]) << 7;              \
      }                                                                         \
    }
    STAGE(0, diag_codes, TBASE_D)
    STAGE(1, proc_codes, TBASE_P)
    STAGE(2, med_codes,  TBASE_M)
#undef STAGE
  }
  __syncthreads();

  // ---- gather: one 32-lane half per visit; 128B bf16 TW rows, 8 lanes/row ----
  const int half = tid >> 5;        // visit 0..15
  const int ln = tid & 31;
  const int oct = ln >> 3;          // code slot 0..3
  const int sl = ln & 7;            // dim slice: dims sl*8 .. sl*8+7
  const unsigned char* twb = ws + TW_OFF;

  float A[8] = {0.f, 0.f, 0.f, 0.f, 0.f, 0.f, 0.f, 0.f};

  if (stAll) {
    const int s = csL[half], e = csL[half + 1];
    for (int jj = s; jj < e; jj += 16) {
      const int j0 = jj + oct, j1 = jj + 4 + oct, j2 = jj + 8 + oct, j3 = jj + 12 + oct;
      const int i0 = (j0 < e) ? j0 : (e - 1);
      const int i1 = (j1 < e) ? j1 : (e - 1);
      const int i2 = (j2 < e) ? j2 : (e - 1);
      const int i3 = (j3 < e) ? j3 : (e - 1);
      const u32x4 t0 = *(const u32x4*)(twb + twoffL[i0] + sl * 16);
      const u32x4 t1 = *(const u32x4*)(twb + twoffL[i1] + sl * 16);
      const u32x4 t2 = *(const u32x4*)(twb + twoffL[i2] + sl * 16);
      const u32x4 t3 = *(const u32x4*)(twb + twoffL[i3] + sl * 16);
      acc8m(t0, (j0 < e) ? 1.f : 0.f, A);
      acc8m(t1, (j1 < e) ? 1.f : 0.f, A);
      acc8m(t2, (j2 < e) ? 1.f : 0.f, A);
      acc8m(t3, (j3 < e) ? 1.f : 0.f, A);
    }
  } else {
    // rare fallback: per-table masked loops, codes from global
#define GFB(T, CG, TBASE)                                                       \
    {                                                                           \
      const int s = offsL[T][half], e = offsL[T][half + 1];                     \
      for (int jj = s; jj < e; jj += 8) {                                       \
        const int j0 = jj + oct, j1 = jj + 4 + oct;                             \
        const int i0 = (j0 < e) ? j0 : (e - 1);                                 \
        const int i1 = (j1 < e) ? j1 : (e - 1);                                 \
        const int o0 = (TBASE + CG[i0]) << 7;                                   \
        const int o1 = (TBASE + CG[i1]) << 7;                                   \
        const u32x4 t0 = *(const u32x4*)(twb + o0 + sl * 16);                   \
        const u32x4 t1 = *(const u32x4*)(twb + o1 + sl * 16);                   \
        acc8m(t0, (j0 < e) ? 1.f : 0.f, A);                                     \
        acc8m(t1, (j1 < e) ? 1.f : 0.f, A);                                     \
      }                                                                         \
    }
    GFB(0, diag_codes, TBASE_D)
    GFB(1, proc_codes, TBASE_P)
    GFB(2, med_codes,  TBASE_M)
#undef GFB
  }

  // reduce across the 4 code slots (octets)
  #pragma unroll
  for (int d = 0; d < 8; ++d) {
    A[d] += __shfl_xor(A[d], 8);
    A[d] += __shfl_xor(A[d], 16);
  }
  if (ln < 8) {
    const f32x4 bb0 = *(const f32x4*)(b1 + sl * 8);
    const f32x4 bb1 = *(const f32x4*)(b1 + sl * 8 + 4);
    u32x4 o;
    o[0] = (u32)f2bf(fmaxf(A[0] + bb0[0], 0.f)) | ((u32)f2bf(fmaxf(A[1] + bb0[1], 0.f)) << 16);
    o[1] = (u32)f2bf(fmaxf(A[2] + bb0[2], 0.f)) | ((u32)f2bf(fmaxf(A[3] + bb0[3], 0.f)) << 16);
    o[2] = (u32)f2bf(fmaxf(A[4] + bb1[0], 0.f)) | ((u32)f2bf(fmaxf(A[5] + bb1[1], 0.f)) << 16);
    o[3] = (u32)f2bf(fmaxf(A[6] + bb1[2], 0.f)) | ((u32)f2bf(fmaxf(A[7] + bb1[3], 0.f)) << 16);
    *(u32x4*)&hs[half][sl * 8] = o;
  }
  __syncthreads();

  // ---- GEMM2 (8 waves): out[16][153] = sigmoid(h @ W2 + b2); 10 N-tiles ----
  // A frag: row=l&15, k=(l>>4)*8+e.  B pre-swizzled.  D: col=l&15, row=(l>>4)*4+reg.
  const int jloc = l & 15;
  const int kq = l >> 4;
  const s16x8* w2f = (const s16x8*)(ws + W2F_OFF);

  for (int t = wv; t < 10; t += 8) {
    const int n = t * 16 + jloc;
    const bool nok = (n < MED);
    const s16x8 bw0 = w2f[(t * 2 + 0) * 64 + l];
    const s16x8 bw1 = w2f[(t * 2 + 1) * 64 + l];
    f32x4 o0 = {0.f, 0.f, 0.f, 0.f};
    {
      const int ko = kq * 8;
      const s16x8 a00 = *(const s16x8*)&hs[jloc][ko];
      o0 = __builtin_amdgcn_mfma_f32_16x16x32_bf16(a00, bw0, o0, 0, 0, 0);
      const s16x8 a01 = *(const s16x8*)&hs[jloc][ko + 32];
      o0 = __builtin_amdgcn_mfma_f32_16x16x32_bf16(a01, bw1, o0, 0, 0, 0);
    }
    if (nok) {
      const float bias2 = b2[n];
      #pragma unroll
      for (int r = 0; r < 4; ++r) {
        const int row = kq * 4 + r;
        const float z0 = o0[r] + bias2;
        out[(size_t)(b0 + row) * MED + n] = 1.f / (1.f + __expf(-z0));
      }
    }
  }
}

// ============== fallback (round-4 kernel, f32 tables, no ws) ==============
#define CAPD 640
#define CAPP 384
#define CAPM 512
#define CAPT_FB (CAPD + CAPP + CAPM)

__global__ __launch_bounds__(NTHR, 8) void fused_ehr_fb(
    const int* __restrict__ diag_codes, const int* __restrict__ diag_seg,
    const int* __restrict__ proc_codes, const int* __restrict__ proc_seg,
    const int* __restrict__ med_codes,  const int* __restrict__ med_seg,
    const float* __restrict__ diag_table, const float* __restrict__ proc_table,
    const float* __restrict__ med_table,
    const float* __restrict__ W1, const float* __restrict__ b1,
    const float* __restrict__ W2, const float* __restrict__ b2,
    float* __restrict__ out, int ND, int NP, int NM)
{
  __shared__ __align__(16) unsigned short xs[VPB][K1 + 8];
  __shared__ __align__(16) unsigned short hs[VPB][HID + 8];
  __shared__ int offs[3][VPB + 1];
  __shared__ int codesL[CAPT_FB];

  const int tid = threadIdx.x;
  const int l = tid & 63;
  const int wv = tid >> 6;
  const int b0 = blockIdx.x * VPB;

  if (wv < 6) {
    const int T = wv >> 1, w = wv & 1;
    const int* seg = (T == 0) ? diag_seg : (T == 1) ? proc_seg : med_seg;
    const int n = (T == 0) ? ND : (T == 1) ? NP : NM;
    const int r = lb_wave(seg, n, b0 + (w ? VPB : 0), l);
    if (l == 0) offs[T][w ? VPB : 0] = r;
  }
  __syncthreads();

  const int sD = offs[0][0], cntD = offs[0][VPB] - sD;
  const int sP = offs[1][0], cntP = offs[1][VPB] - sP;
  const int sM = offs[2][0], cntM = offs[2][VPB] - sM;
  const bool stD = (cntD <= CAPD), stP = (cntP <= CAPP), stM = (cntM <= CAPM);

  if (tid < 3 * (VPB - 1)) {
    const int T = tid / (VPB - 1), idx = tid - T * (VPB - 1) + 1;
    offs[T][idx] = offs[T][VPB];
  }
  if (stD) for (int i = tid; i < cntD; i += NTHR) codesL[i] = diag_codes[sD + i];
  if (stP) for (int i = tid; i < cntP; i += NTHR) codesL[CAPD + i] = proc_codes[sP + i];
  if (stM) for (int i = tid; i < cntM; i += NTHR) codesL[CAPD + CAPP + i] = med_codes[sM + i];
  __syncthreads();

#define MARK(Tidx, STAGED, CNT, SBASE, SEGG, NT)                                 \
  if (STAGED) {                                                                  \
    for (int i = tid; i < CNT; i += NTHR) {                                      \
      const int v1 = SEGG[SBASE + i];                                            \
      const int v0_ = (i == 0) ? (b0 - 1) : SEGG[SBASE + i - 1];                 \
      int klo = v0_ + 1; if (klo < b0 + 1) klo = b0 + 1;                         \
      int khi = v1;      if (khi > b0 + VPB - 1) khi = b0 + VPB - 1;             \
      for (int k = klo; k <= khi; ++k) offs[Tidx][k - b0] = SBASE + i;           \
    }                                                                            \
  } else if (tid < VPB - 1) {                                                    \
    offs[Tidx][tid + 1] = lb_fast_scalar(SEGG, NT, b0 + tid + 1);                \
  }

  MARK(0, stD, cntD, sD, diag_seg, ND)
  MARK(1, stP, cntP, sP, proc_seg, NP)
  MARK(2, stM, cntM, sM, med_seg,  NM)
#undef MARK
  __syncthreads();

  const int half = tid >> 5;
  const int ln = tid & 31;

#define GATH(T, CODES_G, TBL, STAGED, SGLOB, LBASE)                               \
  {                                                                               \
    const int s_ = offs[T][half], e_ = offs[T][half + 1];                         \
    float a0 = 0.f, a1 = 0.f, a2 = 0.f, a3 = 0.f;                                 \
    int i = s_;                                                                   \
    if (STAGED) {                                                                 \
      const int lb = LBASE - SGLOB;                                               \
      for (; i + 3 < e_; i += 4) {                                                \
        const int c0 = codesL[lb + i],     c1 = codesL[lb + i + 1];               \
        const int c2 = codesL[lb + i + 2], c3 = codesL[lb + i + 3];               \
        const f32x4 t0 = *(const f32x4*)(TBL + (size_t)c0 * EMB + ln * 4);        \
        const f32x4 t1 = *(const f32x4*)(TBL + (size_t)c1 * EMB + ln * 4);        \
        const f32x4 t2 = *(const f32x4*)(TBL + (size_t)c2 * EMB + ln * 4);        \
        const f32x4 t3 = *(const f32x4*)(TBL + (size_t)c3 * EMB + ln * 4);        \
        a0 += (t0[0] + t1[0]) + (t2[0] + t3[0]);                                  \
        a1 += (t0[1] + t1[1]) + (t2[1] + t3[1]);                                  \
        a2 += (t0[2] + t1[2]) + (t2[2] + t3[2]);                                  \
        a3 += (t0[3] + t1[3]) + (t2[3] + t3[3]);                                  \
      }                                                                           \
      for (; i < e_; ++i) {                                                       \
        const int c = codesL[lb + i];                                             \
        const f32x4 t = *(const f32x4*)(TBL + (size_t)c * EMB + ln * 4);          \
        a0 += t[0]; a1 += t[1]; a2 += t[2]; a3 += t[3];                           \
      }                                                                           \
    } else {                                                                      \
      for (; i < e_; ++i) {                                                       \
        const int c = CODES_G[i];                                                 \
        const f32x4 t = *(const f32x4*)(TBL + (size_t)c * EMB + ln * 4);          \
        a0 += t[0]; a1 += t[1]; a2 += t[2]; a3 += t[3];                           \
      }                                                                           \
    }                                                                             \
    const u32 p0 = (u32)f2bf(a0) | ((u32)f2bf(a1) << 16);                         \
    const u32 p1 = (u32)f2bf(a2) | ((u32)f2bf(a3) << 16);                         \
    uint2* d_ = (uint2*)&xs[half][T * EMB + ln * 4];                              \
    *d_ = make_uint2(p0, p1);                                                     \
  }

  GATH(0, diag_codes, diag_table, stD, sD, 0)
  GATH(1, proc_codes, proc_table, stP, sP, CAPD)
  GATH(2, med_codes,  med_table,  stM, sM, CAPD + CAPP)
#undef GATH
  __syncthreads();

  const int jloc = l & 15;
  const int kq = l >> 4;

  if (wv < 4) {
    const int j1 = wv * 16 + jloc;
    f32x4 acc = {0.f, 0.f, 0.f, 0.f};
    s16x8 bf;
    #pragma unroll
    for (int e = 0; e < 8; ++e)
      bf[e] = (short)f2bf(W1[(size_t)(kq * 8 + e) * HID + j1]);
    #pragma unroll
    for (int kt = 0; kt < 12; ++kt) {
      s16x8 nxt;
      if (kt < 11) {
        const int kb = (kt + 1) * 32 + kq * 8;
        #pragma unroll
        for (int e = 0; e < 8; ++e)
          nxt[e] = (short)f2bf(W1[(size_t)(kb + e) * HID + j1]);
      }
      const s16x8 a0 = *(const s16x8*)&xs[jloc][kt * 32 + kq * 8];
      acc = __builtin_amdgcn_mfma_f32_16x16x32_bf16(a0, bf, acc, 0, 0, 0);
      if (kt < 11) bf = nxt;
    }
    const float bias1 = b1[j1];
    #pragma unroll
    for (int r = 0; r < 4; ++r)
      hs[kq * 4 + r][j1] = f2bf(fmaxf(acc[r] + bias1, 0.f));
  }
  __syncthreads();

  for (int t = wv; t < 10; t += 8) {
    const int n = t * 16 + jloc;
    const bool nok = (n < MED);
    s16x8 bw0, bw1;
    #pragma unroll
    for (int e = 0; e < 8; ++e) {
      const int k0 = kq * 8 + e;
      bw0[e] = nok ? (short)f2bf(W2[(size_t)k0 * MED + n])        : (short)0;
      bw1[e] = nok ? (short)f2bf(W2[(size_t)(k0 + 32) * MED + n]) : (short)0;
    }
    f32x4 o0 = {0.f, 0.f, 0.f, 0.f};
    {
      const int ko = kq * 8;
      const s16x8 a00 = *(const s16x8*)&hs[jloc][ko];
      o0 = __builtin_amdgcn_mfma_f32_16x16x32_bf16(a00, bw0, o0, 0, 0, 0);
      const s16x8 a01 = *(const s16x8*)&hs[jloc][ko + 32];
      o0 = __builtin_amdgcn_mfma_f32_16x16x32_bf16(a01, bw1, o0, 0, 0, 0);
    }
    if (nok) {
      const float bias2 = b2[n];
      #pragma unroll
      for (int r = 0; r < 4; ++r) {
        const int row = kq * 4 + r;
        const float z0 = o0[r] + bias2;
        out[(size_t)(b0 + row) * MED + n] = 1.f / (1.f + __expf(-z0));
      }
    }
  }
}

extern "C" void kernel_launch(void* const* d_in, const int* in_sizes, int n_in,
                              void* d_out, int out_size, void* d_ws, size_t ws_size,
                              hipStream_t stream) {
  const int* diag_codes = (const int*)d_in[0];
  const int* diag_seg   = (const int*)d_in[1];
  const int* proc_codes = (const int*)d_in[2];
  const int* proc_seg   = (const int*)d_in[3];
  const int* med_codes  = (const int*)d_in[4];
  const int* med_seg    = (const int*)d_in[5];
  const float* diag_table = (const float*)d_in[6];
  const float* proc_table = (const float*)d_in[7];
  const float* med_table  = (const float*)d_in[8];
  const float* W1 = (const float*)d_in[9];
  const float* b1 = (const float*)d_in[10];
  const float* W2 = (const float*)d_in[11];
  const float* b2 = (const float*)d_in[12];
  float* out = (float*)d_out;

  if (ws_size >= WS_NEED) {
    unsigned char* ws = (unsigned char*)d_ws;
    prep_kernel<<<dim3(PREP_BLKS), dim3(256), 0, stream>>>(
        diag_seg, proc_seg, med_seg,
        diag_table, proc_table, med_table, W1, W2, ws,
        in_sizes[0], in_sizes[2], in_sizes[4]);
    fused_ehr_v7<<<dim3(NBLK), dim3(NTHR), 0, stream>>>(
        diag_codes, proc_codes, med_codes, b1, b2, ws, out);
  } else {
    fused_ehr_fb<<<dim3(NBLK), dim3(NTHR), 0, stream>>>(
        diag_codes, diag_seg, proc_codes, proc_seg, med_codes, med_seg,
        diag_table, proc_table, med_table, W1, b1, W2, b2, out,
        in_sizes[0], in_sizes[2], in_sizes[4]);
  }
}